// Round 1
// baseline (8619.711 us; speedup 1.0000x reference)
//
#include <hip/hip_runtime.h>
#include <math.h>

#define D 768
#define NH 12
#define HD 64
#define NL 6
#define DFF 3072
#define BB 2
#define SS 1024
#define NROWS (BB*SS)   // 2048
#define VOCAB 32000
#define LN_EPS 1e-5f

// ---------------- embedding: x[b,s,:] = tok[idx[b,s]] + pos[s] ----------------
__global__ void embed_kernel(const int* __restrict__ idx, const float* __restrict__ tok,
                             const float* __restrict__ pos, float* __restrict__ x) {
    int row = blockIdx.x;          // 0..NROWS-1
    int s = row % SS;
    int t = idx[row];
    for (int c = threadIdx.x; c < D; c += blockDim.x)
        x[row*D + c] = tok[(size_t)t*D + c] + pos[s*D + c];
}

// ---------------- layernorm over last dim (D=768), one block per row ----------------
__global__ __launch_bounds__(256) void layernorm_kernel(const float* __restrict__ x,
                                                        const float* __restrict__ w,
                                                        const float* __restrict__ b,
                                                        float* __restrict__ out) {
    int row = blockIdx.x;
    __shared__ float l1[4], l2[4];
    int base = row * D;
    float vals[3];
    float s1 = 0.f, s2 = 0.f;
#pragma unroll
    for (int i = 0; i < 3; i++) {
        float v = x[base + threadIdx.x + i*256];
        vals[i] = v; s1 += v; s2 += v*v;
    }
#pragma unroll
    for (int o = 32; o > 0; o >>= 1) {
        s1 += __shfl_down(s1, o, 64);
        s2 += __shfl_down(s2, o, 64);
    }
    if ((threadIdx.x & 63) == 0) { l1[threadIdx.x >> 6] = s1; l2[threadIdx.x >> 6] = s2; }
    __syncthreads();
    float sum   = l1[0] + l1[1] + l1[2] + l1[3];
    float sumsq = l2[0] + l2[1] + l2[2] + l2[3];
    float mu  = sum * (1.f / D);
    float var = sumsq * (1.f / D) - mu * mu;
    float inv = rsqrtf(var + LN_EPS);
#pragma unroll
    for (int i = 0; i < 3; i++) {
        int c = threadIdx.x + i*256;
        out[base + c] = (vals[i] - mu) * inv * w[c] + b[c];
    }
}

// ---------------- GEMM: C[M,N] = (X? X +) relu?( A[M,K] @ W[K,N] + bias[N] ) ----------------
// 64x64 tile, BK=16, 256 threads, 4x4 microtile. M=2048 via blockIdx.y, all dims divide tiles.
template<int RELU, int RESID, int HASB>
__global__ __launch_bounds__(256) void gemm_kernel(const float* __restrict__ A,
                                                   const float* __restrict__ W,
                                                   const float* __restrict__ bias,
                                                   const float* __restrict__ X,
                                                   float* __restrict__ C,
                                                   int N, int K) {
    __shared__ float As[16][64];   // [k][m]
    __shared__ float Ws[16][64];   // [k][n]
    int bm = blockIdx.y * 64, bn = blockIdx.x * 64;
    int tid = threadIdx.x;
    int tr = tid >> 4, tc = tid & 15;
    int arow = tid >> 2;            // 0..63
    int acol = (tid & 3) * 4;       // 0,4,8,12
    int wrow = tid >> 4;            // 0..15
    int wcol = (tid & 15) * 4;      // 0..60
    const float* Aptr = A + (size_t)(bm + arow) * K + acol;
    const float* Wptr = W + (size_t)wrow * N + bn + wcol;
    float acc[4][4] = {};
    for (int k0 = 0; k0 < K; k0 += 16) {
        float4 av = *(const float4*)(Aptr + k0);
        float4 wv = *(const float4*)(Wptr + (size_t)k0 * N);
        __syncthreads();
        As[acol+0][arow] = av.x; As[acol+1][arow] = av.y;
        As[acol+2][arow] = av.z; As[acol+3][arow] = av.w;
        *(float4*)&Ws[wrow][wcol] = wv;
        __syncthreads();
#pragma unroll
        for (int kk = 0; kk < 16; kk++) {
            float a[4], w[4];
#pragma unroll
            for (int i = 0; i < 4; i++) a[i] = As[kk][tr*4 + i];
#pragma unroll
            for (int j = 0; j < 4; j++) w[j] = Ws[kk][tc*4 + j];
#pragma unroll
            for (int i = 0; i < 4; i++)
#pragma unroll
                for (int j = 0; j < 4; j++) acc[i][j] += a[i] * w[j];
        }
    }
#pragma unroll
    for (int i = 0; i < 4; i++) {
        int r = bm + tr*4 + i;
#pragma unroll
        for (int j = 0; j < 4; j++) {
            int c = bn + tc*4 + j;
            float v = acc[i][j];
            if (HASB) v += bias[c];
            if (RESID) v += X[(size_t)r * N + c];
            if (RELU) v = fmaxf(v, 0.f);
            C[(size_t)r * N + c] = v;
        }
    }
}

// ---------------- causal attention, one block (256 thr) per (b,h,q-row) ----------------
// q,k,v stored as [B*S, D] with head h at columns h*HD..h*HD+63.
__global__ __launch_bounds__(256) void attn_kernel(const float* __restrict__ q,
                                                   const float* __restrict__ k,
                                                   const float* __restrict__ v,
                                                   float* __restrict__ y) {
    int r = blockIdx.x;            // (b*NH + h)*SS + qs
    int qs = r % SS;
    int bh = r / SS;
    int b = bh / NH, h = bh % NH;
    int tid = threadIdx.x;
    __shared__ float sc[SS];
    __shared__ float qrow[HD];
    __shared__ float red[4];
    __shared__ float part[4][HD];
    int qbase = (b*SS + qs)*D + h*HD;
    if (tid < HD) qrow[tid] = q[qbase + tid];
    __syncthreads();
    // scores + running max
    float mx = -INFINITY;
    for (int kk = tid; kk <= qs; kk += 256) {
        const float* krow = k + (size_t)(b*SS + kk)*D + h*HD;
        float dot = 0.f;
#pragma unroll
        for (int d2 = 0; d2 < HD; d2 += 4) {
            float4 kv = *(const float4*)(krow + d2);
            dot += qrow[d2]*kv.x + qrow[d2+1]*kv.y + qrow[d2+2]*kv.z + qrow[d2+3]*kv.w;
        }
        dot *= 0.125f;   // 1/sqrt(64)
        sc[kk] = dot;
        mx = fmaxf(mx, dot);
    }
#pragma unroll
    for (int o = 32; o > 0; o >>= 1) mx = fmaxf(mx, __shfl_down(mx, o, 64));
    if ((tid & 63) == 0) red[tid >> 6] = mx;
    __syncthreads();
    mx = fmaxf(fmaxf(red[0], red[1]), fmaxf(red[2], red[3]));
    // exp + sum
    float sum = 0.f;
    for (int kk = tid; kk <= qs; kk += 256) {
        float p = __expf(sc[kk] - mx);
        sc[kk] = p;
        sum += p;
    }
#pragma unroll
    for (int o = 32; o > 0; o >>= 1) sum += __shfl_down(sum, o, 64);
    __syncthreads();
    if ((tid & 63) == 0) red[tid >> 6] = sum;
    __syncthreads();
    sum = red[0] + red[1] + red[2] + red[3];
    float rinv = 1.f / sum;
    // output: o[d] = sum_k p[k] * V[k][d]
    int d2  = tid & 63;
    int prt = tid >> 6;
    float o = 0.f;
    for (int kk = prt; kk <= qs; kk += 4)
        o += sc[kk] * v[(size_t)(b*SS + kk)*D + h*HD + d2];
    part[prt][d2] = o;
    __syncthreads();
    if (tid < HD) {
        float oo = (part[0][tid] + part[1][tid] + part[2][tid] + part[3][tid]) * rinv;
        y[qbase + tid] = oo;
    }
}

extern "C" void kernel_launch(void* const* d_in, const int* in_sizes, int n_in,
                              void* d_out, int out_size, void* d_ws, size_t ws_size,
                              hipStream_t stream) {
    const int*   idx  = (const int*)d_in[0];
    const float* tok  = (const float*)d_in[1];
    const float* pos  = (const float*)d_in[2];
    const float* ln1w = (const float*)d_in[3];
    const float* ln1b = (const float*)d_in[4];
    const float* Wq   = (const float*)d_in[5];
    const float* bq   = (const float*)d_in[6];
    const float* Wk   = (const float*)d_in[7];
    const float* bk   = (const float*)d_in[8];
    const float* Wv   = (const float*)d_in[9];
    const float* bv   = (const float*)d_in[10];
    const float* Wo   = (const float*)d_in[11];
    const float* bo   = (const float*)d_in[12];
    const float* ln2w = (const float*)d_in[13];
    const float* ln2b = (const float*)d_in[14];
    const float* W1   = (const float*)d_in[15];
    const float* b1   = (const float*)d_in[16];
    const float* W2   = (const float*)d_in[17];
    const float* b2   = (const float*)d_in[18];
    const float* lnfw = (const float*)d_in[19];
    const float* lnfb = (const float*)d_in[20];
    const float* lmw  = (const float*)d_in[21];
    float* out = (float*)d_out;

    float* x  = (float*)d_ws;          // [2048,768]
    float* h  = x  + (size_t)NROWS*D;  // [2048,768]
    float* qb = h  + (size_t)NROWS*D;
    float* kb = qb + (size_t)NROWS*D;
    float* vb = kb + (size_t)NROWS*D;
    float* yb = vb + (size_t)NROWS*D;
    float* a1 = yb + (size_t)NROWS*D;  // [2048,3072]

    embed_kernel<<<NROWS, 256, 0, stream>>>(idx, tok, pos, x);

    dim3 gD(D/64, NROWS/64);      // 12 x 32
    dim3 gF(DFF/64, NROWS/64);    // 48 x 32
    dim3 gV(VOCAB/64, NROWS/64);  // 500 x 32

    for (int l = 0; l < NL; l++) {
        size_t wo = (size_t)l * D * D;
        layernorm_kernel<<<NROWS, 256, 0, stream>>>(x, ln1w + l*D, ln1b + l*D, h);
        gemm_kernel<0,0,1><<<gD, 256, 0, stream>>>(h, Wq + wo, bq + l*D, nullptr, qb, D, D);
        gemm_kernel<0,0,1><<<gD, 256, 0, stream>>>(h, Wk + wo, bk + l*D, nullptr, kb, D, D);
        gemm_kernel<0,0,1><<<gD, 256, 0, stream>>>(h, Wv + wo, bv + l*D, nullptr, vb, D, D);
        attn_kernel<<<BB*NH*SS, 256, 0, stream>>>(qb, kb, vb, yb);
        gemm_kernel<0,1,1><<<gD, 256, 0, stream>>>(yb, Wo + wo, bo + l*D, x, x, D, D);
        layernorm_kernel<<<NROWS, 256, 0, stream>>>(x, ln2w + l*D, ln2b + l*D, h);
        gemm_kernel<1,0,1><<<gF, 256, 0, stream>>>(h, W1 + (size_t)l*D*DFF, b1 + l*DFF, nullptr, a1, DFF, D);
        gemm_kernel<0,1,1><<<gD, 256, 0, stream>>>(a1, W2 + (size_t)l*DFF*D, b2 + l*D, x, x, D, DFF);
    }
    layernorm_kernel<<<NROWS, 256, 0, stream>>>(x, lnfw, lnfb, h);
    gemm_kernel<0,0,0><<<gV, 256, 0, stream>>>(h, lmw, nullptr, nullptr, out, VOCAB, D);
}

// Round 2
// 5225.932 us; speedup vs baseline: 1.6494x; 1.6494x over previous
//
#include <hip/hip_runtime.h>
#include <hip/hip_bf16.h>
#include <math.h>

#define D 768
#define NH 12
#define HD 64
#define NL 6
#define DFF 3072
#define BB 2
#define SS 1024
#define NROWS (BB*SS)   // 2048
#define VOCAB 32000
#define QKVN (3*D)      // 2304
#define LN_EPS 1e-5f

typedef __attribute__((ext_vector_type(8))) short bf16x8;
typedef __attribute__((ext_vector_type(4))) float f32x4;

typedef __attribute__((address_space(1))) const unsigned char* gas_ptr;
typedef __attribute__((address_space(3))) unsigned char* las_ptr;

__device__ __forceinline__ void load_lds16(const void* g, void* l) {
    __builtin_amdgcn_global_load_lds((gas_ptr)g, (las_ptr)l, 16, 0, 0);
}

__device__ __forceinline__ void storeOut(float* p, float v) { *p = v; }
__device__ __forceinline__ void storeOut(__hip_bfloat16* p, float v) { *p = __float2bfloat16(v); }

// ---------------- embedding ----------------
__global__ void embed_kernel(const int* __restrict__ idx, const float* __restrict__ tok,
                             const float* __restrict__ pos, float* __restrict__ x) {
    int row = blockIdx.x;
    int s = row % SS;
    int t = idx[row];
    for (int c = threadIdx.x; c < D; c += blockDim.x)
        x[row*D + c] = tok[(size_t)t*D + c] + pos[s*D + c];
}

// ---------------- layernorm (row of 768), templated output ----------------
template<typename OT>
__global__ __launch_bounds__(256) void layernorm_kernel(const float* __restrict__ x,
                                                        const float* __restrict__ w,
                                                        const float* __restrict__ b,
                                                        OT* __restrict__ out) {
    int row = blockIdx.x;
    __shared__ float l1[4], l2[4];
    int base = row * D;
    float vals[3];
    float s1 = 0.f, s2 = 0.f;
#pragma unroll
    for (int i = 0; i < 3; i++) {
        float v = x[base + threadIdx.x + i*256];
        vals[i] = v; s1 += v; s2 += v*v;
    }
#pragma unroll
    for (int o = 32; o > 0; o >>= 1) {
        s1 += __shfl_down(s1, o, 64);
        s2 += __shfl_down(s2, o, 64);
    }
    if ((threadIdx.x & 63) == 0) { l1[threadIdx.x >> 6] = s1; l2[threadIdx.x >> 6] = s2; }
    __syncthreads();
    float sum   = l1[0] + l1[1] + l1[2] + l1[3];
    float sumsq = l2[0] + l2[1] + l2[2] + l2[3];
    float mu  = sum * (1.f / D);
    float var = sumsq * (1.f / D) - mu * mu;
    float inv = rsqrtf(var + LN_EPS);
#pragma unroll
    for (int i = 0; i < 3; i++) {
        int c = threadIdx.x + i*256;
        storeOut(&out[base + c], (vals[i] - mu) * inv * w[c] + b[c]);
    }
}

// ---------------- transpose + fp32->bf16: src [K,N] -> dst [N,K] ----------------
__global__ __launch_bounds__(256) void transpose_cvt(const float* __restrict__ src,
                                                     __hip_bfloat16* __restrict__ dst,
                                                     int K, int N,
                                                     size_t srcLayerStride, size_t dstLayerStride,
                                                     int dstRowOff) {
    int l = blockIdx.z;
    src += (size_t)l * srcLayerStride;
    dst += (size_t)l * dstLayerStride + (size_t)dstRowOff * K;
    __shared__ float t[32][33];
    int k0 = blockIdx.x*32, n0 = blockIdx.y*32;
    int tx = threadIdx.x & 31, ty = threadIdx.x >> 5;   // 32x8
    for (int i = ty; i < 32; i += 8) t[i][tx] = src[(size_t)(k0+i)*N + n0+tx];
    __syncthreads();
    for (int i = ty; i < 32; i += 8) dst[(size_t)(n0+i)*K + k0+tx] = __float2bfloat16(t[tx][i]);
}

// ---------------- pack qkv bias: [L,768]x3 -> [L,2304] ----------------
__global__ void pack_qkv_bias(const float* __restrict__ bq, const float* __restrict__ bk,
                              const float* __restrict__ bv, float* __restrict__ dst) {
    int l = blockIdx.y;
    int i = blockIdx.x*256 + threadIdx.x;   // 0..767
    dst[l*QKVN + i]         = bq[l*D + i];
    dst[l*QKVN + D + i]     = bk[l*D + i];
    dst[l*QKVN + 2*D + i]   = bv[l*D + i];
}

// ---------------- bf16 MFMA GEMM: C[M,N] = epilogue(A[M,K] @ BT[N,K]^T) ----------------
// 128x128 tile, BK=32, 256 threads (4 waves, 2x2), 16x16x32 MFMA, global_load_lds w=16.
template<typename OT, int RELU, int RESID, int HASB>
__global__ __launch_bounds__(256) void gemm_mfma(const ushort* __restrict__ A,
                                                 const ushort* __restrict__ BT,
                                                 const float* __restrict__ bias,
                                                 const float* __restrict__ X,
                                                 OT* __restrict__ C,
                                                 int N, int K) {
    __shared__ ushort As[128][32];   // [m][k] bf16
    __shared__ ushort Bs[128][32];   // [n][k] bf16
    int bm = blockIdx.y * 128, bn = blockIdx.x * 128;
    int tid = threadIdx.x;
    int lane = tid & 63, wid = tid >> 6;
    int wr = wid >> 1, wc = wid & 1;         // 2x2 wave grid, each wave 64x64
    int lrow = lane >> 2;                    // 0..15 (staging row within 16-row chunk)
    int lcol = (lane & 3) * 8;               // staging col (elements)
    int fr = lane & 15, fc = lane >> 4;      // fragment row/col-chunk

    f32x4 acc[4][4];
#pragma unroll
    for (int i = 0; i < 4; i++)
#pragma unroll
        for (int j = 0; j < 4; j++)
#pragma unroll
            for (int r = 0; r < 4; r++) acc[i][j][r] = 0.f;

    for (int k0 = 0; k0 < K; k0 += 32) {
#pragma unroll
        for (int i = 0; i < 2; i++) {
            int rt = wid*32 + i*16;          // wave-uniform row base
            load_lds16(A  + (size_t)(bm + rt + lrow)*K + k0 + lcol, &As[rt][0]);
            load_lds16(BT + (size_t)(bn + rt + lrow)*K + k0 + lcol, &Bs[rt][0]);
        }
        asm volatile("s_waitcnt vmcnt(0)" ::: "memory");
        __syncthreads();
        bf16x8 af[4], bf[4];
#pragma unroll
        for (int mi = 0; mi < 4; mi++) af[mi] = *(const bf16x8*)&As[wr*64 + mi*16 + fr][fc*8];
#pragma unroll
        for (int ni = 0; ni < 4; ni++) bf[ni] = *(const bf16x8*)&Bs[wc*64 + ni*16 + fr][fc*8];
#pragma unroll
        for (int mi = 0; mi < 4; mi++)
#pragma unroll
            for (int ni = 0; ni < 4; ni++)
                acc[mi][ni] = __builtin_amdgcn_mfma_f32_16x16x32_bf16(af[mi], bf[ni], acc[mi][ni], 0, 0, 0);
        __syncthreads();
    }
    // epilogue: C/D layout col=lane&15, row=(lane>>4)*4+reg
#pragma unroll
    for (int mi = 0; mi < 4; mi++) {
#pragma unroll
        for (int r = 0; r < 4; r++) {
            int row = bm + wr*64 + mi*16 + fc*4 + r;
#pragma unroll
            for (int ni = 0; ni < 4; ni++) {
                int col = bn + wc*64 + ni*16 + fr;
                float v = acc[mi][ni][r];
                if (HASB) v += bias[col];
                if (RESID) v += X[(size_t)row * N + col];
                if (RELU) v = fmaxf(v, 0.f);
                storeOut(&C[(size_t)row * N + col], v);
            }
        }
    }
}

// ---------------- causal attention (fp32 qkv packed [2048][2304]), bf16 y out ----------------
__global__ __launch_bounds__(256) void attn_kernel(const float* __restrict__ qkv,
                                                   __hip_bfloat16* __restrict__ y) {
    int r = blockIdx.x;            // (b*NH + h)*SS + qs
    int qs = r % SS;
    int bh = r / SS;
    int b = bh / NH, h = bh % NH;
    int tid = threadIdx.x;
    __shared__ float sc[SS];
    __shared__ float qrow[HD];
    __shared__ float red[4];
    __shared__ float part[4][HD];
    size_t qbase = (size_t)(b*SS + qs)*QKVN + h*HD;
    if (tid < HD) qrow[tid] = qkv[qbase + tid];
    __syncthreads();
    float mx = -INFINITY;
    for (int kk = tid; kk <= qs; kk += 256) {
        const float* krow = qkv + (size_t)(b*SS + kk)*QKVN + D + h*HD;
        float dot = 0.f;
#pragma unroll
        for (int d2 = 0; d2 < HD; d2 += 4) {
            float4 kv = *(const float4*)(krow + d2);
            dot += qrow[d2]*kv.x + qrow[d2+1]*kv.y + qrow[d2+2]*kv.z + qrow[d2+3]*kv.w;
        }
        dot *= 0.125f;
        sc[kk] = dot;
        mx = fmaxf(mx, dot);
    }
#pragma unroll
    for (int o = 32; o > 0; o >>= 1) mx = fmaxf(mx, __shfl_down(mx, o, 64));
    if ((tid & 63) == 0) red[tid >> 6] = mx;
    __syncthreads();
    mx = fmaxf(fmaxf(red[0], red[1]), fmaxf(red[2], red[3]));
    float sum = 0.f;
    for (int kk = tid; kk <= qs; kk += 256) {
        float p = __expf(sc[kk] - mx);
        sc[kk] = p;
        sum += p;
    }
#pragma unroll
    for (int o = 32; o > 0; o >>= 1) sum += __shfl_down(sum, o, 64);
    __syncthreads();
    if ((tid & 63) == 0) red[tid >> 6] = sum;
    __syncthreads();
    sum = red[0] + red[1] + red[2] + red[3];
    float rinv = 1.f / sum;
    int d2  = tid & 63;
    int prt = tid >> 6;
    float o = 0.f;
    for (int kk = prt; kk <= qs; kk += 4)
        o += sc[kk] * qkv[(size_t)(b*SS + kk)*QKVN + 2*D + h*HD + d2];
    part[prt][d2] = o;
    __syncthreads();
    if (tid < HD)
        y[(size_t)(b*SS + qs)*D + h*HD + tid] = __float2bfloat16(
            (part[0][tid] + part[1][tid] + part[2][tid] + part[3][tid]) * rinv);
}

extern "C" void kernel_launch(void* const* d_in, const int* in_sizes, int n_in,
                              void* d_out, int out_size, void* d_ws, size_t ws_size,
                              hipStream_t stream) {
    const int*   idx  = (const int*)d_in[0];
    const float* tok  = (const float*)d_in[1];
    const float* pos  = (const float*)d_in[2];
    const float* ln1w = (const float*)d_in[3];
    const float* ln1b = (const float*)d_in[4];
    const float* Wq   = (const float*)d_in[5];
    const float* bq   = (const float*)d_in[6];
    const float* Wk   = (const float*)d_in[7];
    const float* bk   = (const float*)d_in[8];
    const float* Wv   = (const float*)d_in[9];
    const float* bv   = (const float*)d_in[10];
    const float* Wo   = (const float*)d_in[11];
    const float* bo   = (const float*)d_in[12];
    const float* ln2w = (const float*)d_in[13];
    const float* ln2b = (const float*)d_in[14];
    const float* W1   = (const float*)d_in[15];
    const float* b1   = (const float*)d_in[16];
    const float* W2   = (const float*)d_in[17];
    const float* b2   = (const float*)d_in[18];
    const float* lnfw = (const float*)d_in[19];
    const float* lnfb = (const float*)d_in[20];
    const float* lmw  = (const float*)d_in[21];
    float* out = (float*)d_out;

    // ---- workspace carve (bytes) ----
    char* p = (char*)d_ws;
    __hip_bfloat16* qkvT = (__hip_bfloat16*)p; p += (size_t)NL*QKVN*D*2;       // [L][2304][768]
    __hip_bfloat16* WoT  = (__hip_bfloat16*)p; p += (size_t)NL*D*D*2;          // [L][768][768]
    __hip_bfloat16* W1T  = (__hip_bfloat16*)p; p += (size_t)NL*DFF*D*2;        // [L][3072][768]
    __hip_bfloat16* W2T  = (__hip_bfloat16*)p; p += (size_t)NL*D*DFF*2;        // [L][768][3072]
    __hip_bfloat16* lmT  = (__hip_bfloat16*)p; p += (size_t)VOCAB*D*2;         // [32000][768]
    float*          bqkv = (float*)p;          p += (size_t)NL*QKVN*4;         // [L][2304]
    float*          x    = (float*)p;          p += (size_t)NROWS*D*4;
    __hip_bfloat16* h    = (__hip_bfloat16*)p; p += (size_t)NROWS*D*2;
    float*          qkv  = (float*)p;          p += (size_t)NROWS*QKVN*4;
    __hip_bfloat16* yb   = (__hip_bfloat16*)p; p += (size_t)NROWS*D*2;
    __hip_bfloat16* a1   = (__hip_bfloat16*)p; p += (size_t)NROWS*DFF*2;

    // ---- weight conversion / transposition (bf16, [N,K]) ----
    dim3 tDD(D/32, D/32, NL);
    transpose_cvt<<<tDD, 256, 0, stream>>>(Wq, qkvT, D, D, (size_t)D*D, (size_t)QKVN*D, 0);
    transpose_cvt<<<tDD, 256, 0, stream>>>(Wk, qkvT, D, D, (size_t)D*D, (size_t)QKVN*D, D);
    transpose_cvt<<<tDD, 256, 0, stream>>>(Wv, qkvT, D, D, (size_t)D*D, (size_t)QKVN*D, 2*D);
    transpose_cvt<<<tDD, 256, 0, stream>>>(Wo, WoT, D, D, (size_t)D*D, (size_t)D*D, 0);
    transpose_cvt<<<dim3(D/32, DFF/32, NL), 256, 0, stream>>>(W1, W1T, D, DFF, (size_t)D*DFF, (size_t)DFF*D, 0);
    transpose_cvt<<<dim3(DFF/32, D/32, NL), 256, 0, stream>>>(W2, W2T, DFF, D, (size_t)DFF*D, (size_t)D*DFF, 0);
    transpose_cvt<<<dim3(D/32, VOCAB/32, 1), 256, 0, stream>>>(lmw, lmT, D, VOCAB, 0, 0, 0);
    pack_qkv_bias<<<dim3(3, NL), 256, 0, stream>>>(bq, bk, bv, bqkv);

    embed_kernel<<<NROWS, 256, 0, stream>>>(idx, tok, pos, x);

    dim3 gQKV(QKVN/128, NROWS/128);   // 18 x 16
    dim3 gD(D/128, NROWS/128);        // 6 x 16
    dim3 gF(DFF/128, NROWS/128);      // 24 x 16
    dim3 gV(VOCAB/128, NROWS/128);    // 250 x 16

    for (int l = 0; l < NL; l++) {
        layernorm_kernel<<<NROWS, 256, 0, stream>>>(x, ln1w + l*D, ln1b + l*D, h);
        gemm_mfma<float, 0, 0, 1><<<gQKV, 256, 0, stream>>>(
            (const ushort*)h, (const ushort*)(qkvT + (size_t)l*QKVN*D),
            bqkv + (size_t)l*QKVN, nullptr, qkv, QKVN, D);
        attn_kernel<<<BB*NH*SS, 256, 0, stream>>>(qkv, yb);
        gemm_mfma<float, 0, 1, 1><<<gD, 256, 0, stream>>>(
            (const ushort*)yb, (const ushort*)(WoT + (size_t)l*D*D),
            bo + (size_t)l*D, x, x, D, D);
        layernorm_kernel<<<NROWS, 256, 0, stream>>>(x, ln2w + l*D, ln2b + l*D, h);
        gemm_mfma<__hip_bfloat16, 1, 0, 1><<<gF, 256, 0, stream>>>(
            (const ushort*)h, (const ushort*)(W1T + (size_t)l*DFF*D),
            b1 + (size_t)l*DFF, nullptr, a1, DFF, D);
        gemm_mfma<float, 0, 1, 1><<<gD, 256, 0, stream>>>(
            (const ushort*)a1, (const ushort*)(W2T + (size_t)l*D*DFF),
            b2 + (size_t)l*D, x, x, D, DFF);
    }
    layernorm_kernel<<<NROWS, 256, 0, stream>>>(x, lnfw, lnfb, h);
    gemm_mfma<float, 0, 0, 0><<<gV, 256, 0, stream>>>(
        (const ushort*)h, (const ushort*)lmT, nullptr, nullptr, out, VOCAB, D);
}

// Round 3
// 1643.373 us; speedup vs baseline: 5.2451x; 3.1800x over previous
//
#include <hip/hip_runtime.h>
#include <hip/hip_bf16.h>
#include <math.h>

#define D 768
#define NH 12
#define HD 64
#define NL 6
#define DFF 3072
#define BB 2
#define SS 1024
#define NROWS (BB*SS)   // 2048
#define VOCAB 32000
#define QKVN (3*D)      // 2304
#define LN_EPS 1e-5f

typedef __attribute__((ext_vector_type(8))) short bf16x8;
typedef __attribute__((ext_vector_type(4))) float f32x4;

typedef __attribute__((address_space(1))) const unsigned char* gas_ptr;
typedef __attribute__((address_space(3))) unsigned char* las_ptr;

__device__ __forceinline__ void load_lds16(const void* g, void* l) {
    __builtin_amdgcn_global_load_lds((gas_ptr)g, (las_ptr)l, 16, 0, 0);
}

__device__ __forceinline__ void storeOut(float* p, float v) { *p = v; }
__device__ __forceinline__ void storeOut(__hip_bfloat16* p, float v) { *p = __float2bfloat16(v); }
__device__ __forceinline__ ushort f2bs(float f) {
    __hip_bfloat16 h = __float2bfloat16(f);
    return *(ushort*)&h;
}

// ---------------- embedding ----------------
__global__ void embed_kernel(const int* __restrict__ idx, const float* __restrict__ tok,
                             const float* __restrict__ pos, float* __restrict__ x) {
    int row = blockIdx.x;
    int s = row % SS;
    int t = idx[row];
    for (int c = threadIdx.x; c < D; c += blockDim.x)
        x[row*D + c] = tok[(size_t)t*D + c] + pos[s*D + c];
}

// ---------------- layernorm (row of 768), templated output ----------------
template<typename OT>
__global__ __launch_bounds__(256) void layernorm_kernel(const float* __restrict__ x,
                                                        const float* __restrict__ w,
                                                        const float* __restrict__ b,
                                                        OT* __restrict__ out) {
    int row = blockIdx.x;
    __shared__ float l1[4], l2[4];
    int base = row * D;
    float vals[3];
    float s1 = 0.f, s2 = 0.f;
#pragma unroll
    for (int i = 0; i < 3; i++) {
        float v = x[base + threadIdx.x + i*256];
        vals[i] = v; s1 += v; s2 += v*v;
    }
#pragma unroll
    for (int o = 32; o > 0; o >>= 1) {
        s1 += __shfl_down(s1, o, 64);
        s2 += __shfl_down(s2, o, 64);
    }
    if ((threadIdx.x & 63) == 0) { l1[threadIdx.x >> 6] = s1; l2[threadIdx.x >> 6] = s2; }
    __syncthreads();
    float sum   = l1[0] + l1[1] + l1[2] + l1[3];
    float sumsq = l2[0] + l2[1] + l2[2] + l2[3];
    float mu  = sum * (1.f / D);
    float var = sumsq * (1.f / D) - mu * mu;
    float inv = rsqrtf(var + LN_EPS);
#pragma unroll
    for (int i = 0; i < 3; i++) {
        int c = threadIdx.x + i*256;
        storeOut(&out[base + c], (vals[i] - mu) * inv * w[c] + b[c]);
    }
}

// ---------------- transpose + fp32->bf16: src [K,N] -> dst [N,K] ----------------
__global__ __launch_bounds__(256) void transpose_cvt(const float* __restrict__ src,
                                                     __hip_bfloat16* __restrict__ dst,
                                                     int K, int N,
                                                     size_t srcLayerStride, size_t dstLayerStride,
                                                     int dstRowOff) {
    int l = blockIdx.z;
    src += (size_t)l * srcLayerStride;
    dst += (size_t)l * dstLayerStride + (size_t)dstRowOff * K;
    __shared__ float t[32][33];
    int k0 = blockIdx.x*32, n0 = blockIdx.y*32;
    int tx = threadIdx.x & 31, ty = threadIdx.x >> 5;   // 32x8
    for (int i = ty; i < 32; i += 8) t[i][tx] = src[(size_t)(k0+i)*N + n0+tx];
    __syncthreads();
    for (int i = ty; i < 32; i += 8) dst[(size_t)(n0+i)*K + k0+tx] = __float2bfloat16(t[tx][i]);
}

// ---------------- pack qkv bias ----------------
__global__ void pack_qkv_bias(const float* __restrict__ bq, const float* __restrict__ bk,
                              const float* __restrict__ bv, float* __restrict__ dst) {
    int l = blockIdx.y;
    int i = blockIdx.x*256 + threadIdx.x;   // 0..767
    dst[l*QKVN + i]         = bq[l*D + i];
    dst[l*QKVN + D + i]     = bk[l*D + i];
    dst[l*QKVN + 2*D + i]   = bv[l*D + i];
}

// ---------------- bf16 MFMA GEMM (128x128 tile, BK=32, 4 waves) ----------------
template<typename OT, int RELU, int RESID, int HASB>
__global__ __launch_bounds__(256) void gemm_mfma(const ushort* __restrict__ A,
                                                 const ushort* __restrict__ BT,
                                                 const float* __restrict__ bias,
                                                 const float* __restrict__ X,
                                                 OT* __restrict__ C,
                                                 int N, int K) {
    __shared__ ushort As[128][32];
    __shared__ ushort Bs[128][32];
    int bm = blockIdx.y * 128, bn = blockIdx.x * 128;
    int tid = threadIdx.x;
    int lane = tid & 63, wid = tid >> 6;
    int wr = wid >> 1, wc = wid & 1;
    int lrow = lane >> 2;
    int lcol = (lane & 3) * 8;
    int fr = lane & 15, fc = lane >> 4;

    f32x4 acc[4][4];
#pragma unroll
    for (int i = 0; i < 4; i++)
#pragma unroll
        for (int j = 0; j < 4; j++)
#pragma unroll
            for (int r = 0; r < 4; r++) acc[i][j][r] = 0.f;

    for (int k0 = 0; k0 < K; k0 += 32) {
#pragma unroll
        for (int i = 0; i < 2; i++) {
            int rt = wid*32 + i*16;
            load_lds16(A  + (size_t)(bm + rt + lrow)*K + k0 + lcol, &As[rt][0]);
            load_lds16(BT + (size_t)(bn + rt + lrow)*K + k0 + lcol, &Bs[rt][0]);
        }
        asm volatile("s_waitcnt vmcnt(0)" ::: "memory");
        __syncthreads();
        bf16x8 af[4], bf[4];
#pragma unroll
        for (int mi = 0; mi < 4; mi++) af[mi] = *(const bf16x8*)&As[wr*64 + mi*16 + fr][fc*8];
#pragma unroll
        for (int ni = 0; ni < 4; ni++) bf[ni] = *(const bf16x8*)&Bs[wc*64 + ni*16 + fr][fc*8];
#pragma unroll
        for (int mi = 0; mi < 4; mi++)
#pragma unroll
            for (int ni = 0; ni < 4; ni++)
                acc[mi][ni] = __builtin_amdgcn_mfma_f32_16x16x32_bf16(af[mi], bf[ni], acc[mi][ni], 0, 0, 0);
        __syncthreads();
    }
#pragma unroll
    for (int mi = 0; mi < 4; mi++) {
#pragma unroll
        for (int r = 0; r < 4; r++) {
            int row = bm + wr*64 + mi*16 + fc*4 + r;
#pragma unroll
            for (int ni = 0; ni < 4; ni++) {
                int col = bn + wc*64 + ni*16 + fr;
                float v = acc[mi][ni][r];
                if (HASB) v += bias[col];
                if (RESID) v += X[(size_t)row * N + col];
                if (RELU) v = fmaxf(v, 0.f);
                storeOut(&C[(size_t)row * N + col], v);
            }
        }
    }
}

// ---------------- flash attention: MFMA, online softmax ----------------
// grid = B*NH*(S/64); block 256 = 4 waves; wave w owns q-rows [w*16, w*16+16)
// of its 64-row q-tile. K tile + V^T tile staged in LDS per 64-wide kv step.
__global__ __launch_bounds__(256) void attn_mfma(const float* __restrict__ qkv,
                                                 __hip_bfloat16* __restrict__ y) {
    const int bx = blockIdx.x;
    const int qt = 15 - (bx & 15);           // heavy tiles first
    const int h  = (bx >> 4) % NH;
    const int b  = bx / (16*NH);
    const int tid  = threadIdx.x;
    const int lane = tid & 63, w = tid >> 6;
    const int fr = lane & 15, fc = lane >> 4;

    __shared__ ushort Qs[64][72];     // [q][d]   (+8 pad: 144B stride, 2-way max)
    __shared__ ushort Ks[64][72];     // [kv][d]
    __shared__ ushort Vs[64][72];     // [d][kv]  (transposed)
    __shared__ ushort Ps[4][16][72];  // per-wave P strip [q][kv]

    const int q0 = qt * 64;
    const int srow = tid >> 2, sfs = tid & 3;  // staging: 4 lanes per row

    // ---- stage Q tile (bf16) ----
    {
        const float* src = qkv + (size_t)(b*SS + q0 + srow)*QKVN + h*HD;
#pragma unroll
        for (int it = 0; it < 4; it++) {
            int d0 = sfs*4 + it*16;
            float4 v4 = *(const float4*)(src + d0);
            ushort4 u;
            u.x = f2bs(v4.x); u.y = f2bs(v4.y); u.z = f2bs(v4.z); u.w = f2bs(v4.w);
            *(ushort4*)&Qs[srow][d0] = u;
        }
    }
    // Q fragments (wave-local rows; no barrier needed: same wave wrote them)
    bf16x8 qf[2];
#pragma unroll
    for (int s = 0; s < 2; s++) qf[s] = *(const bf16x8*)&Qs[w*16 + fr][s*32 + fc*8];

    f32x4 oacc[4];
#pragma unroll
    for (int ni = 0; ni < 4; ni++)
#pragma unroll
        for (int r = 0; r < 4; r++) oacc[ni][r] = 0.f;
    float m[4] = {-INFINITY, -INFINITY, -INFINITY, -INFINITY};
    float l[4] = {0.f, 0.f, 0.f, 0.f};

    for (int kt = 0; kt <= qt; kt++) {
        const int kv0 = kt * 64;
        __syncthreads();   // protect Ks/Vs against prior iteration's reads
        // ---- stage K tile + V^T tile ----
        {
            const float* ksrc = qkv + (size_t)(b*SS + kv0 + srow)*QKVN + D   + h*HD;
            const float* vsrc = qkv + (size_t)(b*SS + kv0 + srow)*QKVN + 2*D + h*HD;
#pragma unroll
            for (int it = 0; it < 4; it++) {
                int d0 = sfs*4 + it*16;
                float4 kv4 = *(const float4*)(ksrc + d0);
                ushort4 u;
                u.x = f2bs(kv4.x); u.y = f2bs(kv4.y); u.z = f2bs(kv4.z); u.w = f2bs(kv4.w);
                *(ushort4*)&Ks[srow][d0] = u;
                float4 vv4 = *(const float4*)(vsrc + d0);
                Vs[d0+0][srow] = f2bs(vv4.x);
                Vs[d0+1][srow] = f2bs(vv4.y);
                Vs[d0+2][srow] = f2bs(vv4.z);
                Vs[d0+3][srow] = f2bs(vv4.w);
            }
        }
        __syncthreads();
        // ---- S = Q K^T (scaled) ----
        f32x4 sacc[4];
#pragma unroll
        for (int ni = 0; ni < 4; ni++)
#pragma unroll
            for (int r = 0; r < 4; r++) sacc[ni][r] = 0.f;
#pragma unroll
        for (int ni = 0; ni < 4; ni++)
#pragma unroll
            for (int s = 0; s < 2; s++) {
                bf16x8 kf = *(const bf16x8*)&Ks[ni*16 + fr][s*32 + fc*8];
                sacc[ni] = __builtin_amdgcn_mfma_f32_16x16x32_bf16(qf[s], kf, sacc[ni], 0, 0, 0);
            }
        // scale + causal mask (only the diagonal tile needs masking)
        if (kt == qt) {
#pragma unroll
            for (int ni = 0; ni < 4; ni++)
#pragma unroll
                for (int r = 0; r < 4; r++) {
                    float v = sacc[ni][r] * 0.125f;
                    sacc[ni][r] = (ni*16 + fr > w*16 + fc*4 + r) ? -INFINITY : v;
                }
        } else {
#pragma unroll
            for (int ni = 0; ni < 4; ni++)
#pragma unroll
                for (int r = 0; r < 4; r++) sacc[ni][r] *= 0.125f;
        }
        // ---- online softmax (rows live in 16-lane fr groups) ----
        float p[4][4];
#pragma unroll
        for (int r = 0; r < 4; r++) {
            float mx = fmaxf(fmaxf(sacc[0][r], sacc[1][r]), fmaxf(sacc[2][r], sacc[3][r]));
#pragma unroll
            for (int o = 1; o < 16; o <<= 1) mx = fmaxf(mx, __shfl_xor(mx, o, 64));
            float mn = fmaxf(m[r], mx);
            float fac = __expf(m[r] - mn);   // 0 when m=-inf
            float rs = 0.f;
#pragma unroll
            for (int ni = 0; ni < 4; ni++) {
                float pv = __expf(sacc[ni][r] - mn);
                p[ni][r] = pv;
                rs += pv;
            }
#pragma unroll
            for (int o = 1; o < 16; o <<= 1) rs += __shfl_xor(rs, o, 64);
            l[r] = l[r] * fac + rs;
            m[r] = mn;
#pragma unroll
            for (int ni = 0; ni < 4; ni++) oacc[ni][r] *= fac;
        }
        // ---- P -> LDS (bf16), wave-local ----
#pragma unroll
        for (int ni = 0; ni < 4; ni++)
#pragma unroll
            for (int r = 0; r < 4; r++)
                Ps[w][fc*4 + r][ni*16 + fr] = f2bs(p[ni][r]);
        // ---- O += P V ----
        bf16x8 pa[2];
#pragma unroll
        for (int s = 0; s < 2; s++) pa[s] = *(const bf16x8*)&Ps[w][fr][s*32 + fc*8];
#pragma unroll
        for (int ni = 0; ni < 4; ni++)
#pragma unroll
            for (int s = 0; s < 2; s++) {
                bf16x8 vf = *(const bf16x8*)&Vs[ni*16 + fr][s*32 + fc*8];
                oacc[ni] = __builtin_amdgcn_mfma_f32_16x16x32_bf16(pa[s], vf, oacc[ni], 0, 0, 0);
            }
    }
    // ---- write O / l ----
#pragma unroll
    for (int r = 0; r < 4; r++) {
        float rinv = 1.f / l[r];
        int row = b*SS + q0 + w*16 + fc*4 + r;
#pragma unroll
        for (int ni = 0; ni < 4; ni++)
            y[(size_t)row*D + h*HD + ni*16 + fr] = __float2bfloat16(oacc[ni][r] * rinv);
    }
}

extern "C" void kernel_launch(void* const* d_in, const int* in_sizes, int n_in,
                              void* d_out, int out_size, void* d_ws, size_t ws_size,
                              hipStream_t stream) {
    const int*   idx  = (const int*)d_in[0];
    const float* tok  = (const float*)d_in[1];
    const float* pos  = (const float*)d_in[2];
    const float* ln1w = (const float*)d_in[3];
    const float* ln1b = (const float*)d_in[4];
    const float* Wq   = (const float*)d_in[5];
    const float* bq   = (const float*)d_in[6];
    const float* Wk   = (const float*)d_in[7];
    const float* bk   = (const float*)d_in[8];
    const float* Wv   = (const float*)d_in[9];
    const float* bv   = (const float*)d_in[10];
    const float* Wo   = (const float*)d_in[11];
    const float* bo   = (const float*)d_in[12];
    const float* ln2w = (const float*)d_in[13];
    const float* ln2b = (const float*)d_in[14];
    const float* W1   = (const float*)d_in[15];
    const float* b1   = (const float*)d_in[16];
    const float* W2   = (const float*)d_in[17];
    const float* b2   = (const float*)d_in[18];
    const float* lnfw = (const float*)d_in[19];
    const float* lnfb = (const float*)d_in[20];
    const float* lmw  = (const float*)d_in[21];
    float* out = (float*)d_out;

    // ---- workspace carve ----
    char* p = (char*)d_ws;
    __hip_bfloat16* qkvT = (__hip_bfloat16*)p; p += (size_t)NL*QKVN*D*2;
    __hip_bfloat16* WoT  = (__hip_bfloat16*)p; p += (size_t)NL*D*D*2;
    __hip_bfloat16* W1T  = (__hip_bfloat16*)p; p += (size_t)NL*DFF*D*2;
    __hip_bfloat16* W2T  = (__hip_bfloat16*)p; p += (size_t)NL*D*DFF*2;
    __hip_bfloat16* lmT  = (__hip_bfloat16*)p; p += (size_t)VOCAB*D*2;
    float*          bqkv = (float*)p;          p += (size_t)NL*QKVN*4;
    float*          x    = (float*)p;          p += (size_t)NROWS*D*4;
    __hip_bfloat16* h    = (__hip_bfloat16*)p; p += (size_t)NROWS*D*2;
    float*          qkv  = (float*)p;          p += (size_t)NROWS*QKVN*4;
    __hip_bfloat16* yb   = (__hip_bfloat16*)p; p += (size_t)NROWS*D*2;
    __hip_bfloat16* a1   = (__hip_bfloat16*)p; p += (size_t)NROWS*DFF*2;

    // ---- weight conversion / transposition ----
    dim3 tDD(D/32, D/32, NL);
    transpose_cvt<<<tDD, 256, 0, stream>>>(Wq, qkvT, D, D, (size_t)D*D, (size_t)QKVN*D, 0);
    transpose_cvt<<<tDD, 256, 0, stream>>>(Wk, qkvT, D, D, (size_t)D*D, (size_t)QKVN*D, D);
    transpose_cvt<<<tDD, 256, 0, stream>>>(Wv, qkvT, D, D, (size_t)D*D, (size_t)QKVN*D, 2*D);
    transpose_cvt<<<tDD, 256, 0, stream>>>(Wo, WoT, D, D, (size_t)D*D, (size_t)D*D, 0);
    transpose_cvt<<<dim3(D/32, DFF/32, NL), 256, 0, stream>>>(W1, W1T, D, DFF, (size_t)D*DFF, (size_t)DFF*D, 0);
    transpose_cvt<<<dim3(DFF/32, D/32, NL), 256, 0, stream>>>(W2, W2T, DFF, D, (size_t)DFF*D, (size_t)D*DFF, 0);
    transpose_cvt<<<dim3(D/32, VOCAB/32, 1), 256, 0, stream>>>(lmw, lmT, D, VOCAB, 0, 0, 0);
    pack_qkv_bias<<<dim3(3, NL), 256, 0, stream>>>(bq, bk, bv, bqkv);

    embed_kernel<<<NROWS, 256, 0, stream>>>(idx, tok, pos, x);

    dim3 gQKV(QKVN/128, NROWS/128);
    dim3 gD(D/128, NROWS/128);
    dim3 gF(DFF/128, NROWS/128);
    dim3 gV(VOCAB/128, NROWS/128);

    for (int l = 0; l < NL; l++) {
        layernorm_kernel<<<NROWS, 256, 0, stream>>>(x, ln1w + l*D, ln1b + l*D, h);
        gemm_mfma<float, 0, 0, 1><<<gQKV, 256, 0, stream>>>(
            (const ushort*)h, (const ushort*)(qkvT + (size_t)l*QKVN*D),
            bqkv + (size_t)l*QKVN, nullptr, qkv, QKVN, D);
        attn_mfma<<<BB*NH*(SS/64), 256, 0, stream>>>(qkv, yb);
        gemm_mfma<float, 0, 1, 1><<<gD, 256, 0, stream>>>(
            (const ushort*)yb, (const ushort*)(WoT + (size_t)l*D*D),
            bo + (size_t)l*D, x, x, D, D);
        layernorm_kernel<<<NROWS, 256, 0, stream>>>(x, ln2w + l*D, ln2b + l*D, h);
        gemm_mfma<__hip_bfloat16, 1, 0, 1><<<gF, 256, 0, stream>>>(
            (const ushort*)h, (const ushort*)(W1T + (size_t)l*DFF*D),
            b1 + (size_t)l*DFF, nullptr, a1, DFF, D);
        gemm_mfma<float, 0, 1, 1><<<gD, 256, 0, stream>>>(
            (const ushort*)a1, (const ushort*)(W2T + (size_t)l*D*DFF),
            b2 + (size_t)l*D, x, x, D, DFF);
    }
    layernorm_kernel<<<NROWS, 256, 0, stream>>>(x, lnfw, lnfb, h);
    gemm_mfma<float, 0, 0, 0><<<gV, 256, 0, stream>>>(
        (const ushort*)h, (const ushort*)lmT, nullptr, nullptr, out, VOCAB, D);
}

// Round 4
// 1408.275 us; speedup vs baseline: 6.1208x; 1.1669x over previous
//
#include <hip/hip_runtime.h>
#include <hip/hip_bf16.h>
#include <math.h>

#define D 768
#define NH 12
#define HD 64
#define NL 6
#define DFF 3072
#define BB 2
#define SS 1024
#define NROWS (BB*SS)   // 2048
#define VOCAB 32000
#define QKVN (3*D)      // 2304
#define LN_EPS 1e-5f

typedef __attribute__((ext_vector_type(8))) short bf16x8;
typedef __attribute__((ext_vector_type(4))) float f32x4;

typedef __attribute__((address_space(1))) const unsigned char* gas_ptr;
typedef __attribute__((address_space(3))) unsigned char* las_ptr;

__device__ __forceinline__ void load_lds16(const void* g, void* l) {
    __builtin_amdgcn_global_load_lds((gas_ptr)g, (las_ptr)l, 16, 0, 0);
}

__device__ __forceinline__ void storeOut(float* p, float v) { *p = v; }
__device__ __forceinline__ void storeOut(__hip_bfloat16* p, float v) { *p = __float2bfloat16(v); }
__device__ __forceinline__ ushort f2bs(float f) {
    __hip_bfloat16 h = __float2bfloat16(f);
    return *(ushort*)&h;
}

// ---------------- embedding ----------------
__global__ void embed_kernel(const int* __restrict__ idx, const float* __restrict__ tok,
                             const float* __restrict__ pos, float* __restrict__ x) {
    int row = blockIdx.x;
    int s = row % SS;
    int t = idx[row];
    for (int c = threadIdx.x; c < D; c += blockDim.x)
        x[row*D + c] = tok[(size_t)t*D + c] + pos[s*D + c];
}

// ---------------- layernorm (row of 768), templated output ----------------
template<typename OT>
__global__ __launch_bounds__(256) void layernorm_kernel(const float* __restrict__ x,
                                                        const float* __restrict__ w,
                                                        const float* __restrict__ b,
                                                        OT* __restrict__ out) {
    int row = blockIdx.x;
    __shared__ float l1[4], l2[4];
    int base = row * D;
    float vals[3];
    float s1 = 0.f, s2 = 0.f;
#pragma unroll
    for (int i = 0; i < 3; i++) {
        float v = x[base + threadIdx.x + i*256];
        vals[i] = v; s1 += v; s2 += v*v;
    }
#pragma unroll
    for (int o = 32; o > 0; o >>= 1) {
        s1 += __shfl_down(s1, o, 64);
        s2 += __shfl_down(s2, o, 64);
    }
    if ((threadIdx.x & 63) == 0) { l1[threadIdx.x >> 6] = s1; l2[threadIdx.x >> 6] = s2; }
    __syncthreads();
    float sum   = l1[0] + l1[1] + l1[2] + l1[3];
    float sumsq = l2[0] + l2[1] + l2[2] + l2[3];
    float mu  = sum * (1.f / D);
    float var = sumsq * (1.f / D) - mu * mu;
    float inv = rsqrtf(var + LN_EPS);
#pragma unroll
    for (int i = 0; i < 3; i++) {
        int c = threadIdx.x + i*256;
        storeOut(&out[base + c], (vals[i] - mu) * inv * w[c] + b[c]);
    }
}

// ---------------- transpose + fp32->bf16: src [K,N] -> dst [N,K] ----------------
__global__ __launch_bounds__(256) void transpose_cvt(const float* __restrict__ src,
                                                     __hip_bfloat16* __restrict__ dst,
                                                     int K, int N,
                                                     size_t srcLayerStride, size_t dstLayerStride,
                                                     int dstRowOff) {
    int l = blockIdx.z;
    src += (size_t)l * srcLayerStride;
    dst += (size_t)l * dstLayerStride + (size_t)dstRowOff * K;
    __shared__ float t[32][33];
    int k0 = blockIdx.x*32, n0 = blockIdx.y*32;
    int tx = threadIdx.x & 31, ty = threadIdx.x >> 5;   // 32x8
    for (int i = ty; i < 32; i += 8) t[i][tx] = src[(size_t)(k0+i)*N + n0+tx];
    __syncthreads();
    for (int i = ty; i < 32; i += 8) dst[(size_t)(n0+i)*K + k0+tx] = __float2bfloat16(t[tx][i]);
}

// ---------------- pack qkv bias ----------------
__global__ void pack_qkv_bias(const float* __restrict__ bq, const float* __restrict__ bk,
                              const float* __restrict__ bv, float* __restrict__ dst) {
    int l = blockIdx.y;
    int i = blockIdx.x*256 + threadIdx.x;   // 0..767
    dst[l*QKVN + i]         = bq[l*D + i];
    dst[l*QKVN + D + i]     = bk[l*D + i];
    dst[l*QKVN + 2*D + i]   = bv[l*D + i];
}

// ---------------- bf16 MFMA GEMM, templated tile (BM,BN in {64,128}) ----------------
// 1D grid (nwg % 8 == 0), XCD-bijective swizzle; CMAJ=1 walks M fastest within
// an XCD chunk (for B >> A GEMMs: each XCD keeps an N-slice of B L2-resident).
// 256 threads = 4 waves in 2x2; wave tile (BM/2)x(BN/2); 16x16x32 bf16 MFMA.
template<int BM, int BN, int CMAJ, typename OT, int RELU, int RESID, int HASB>
__global__ __launch_bounds__(256) void gemm_mfma(const ushort* __restrict__ A,
                                                 const ushort* __restrict__ BT,
                                                 const float* __restrict__ bias,
                                                 const float* __restrict__ X,
                                                 OT* __restrict__ C,
                                                 int N, int K, int gx, int gy) {
    constexpr int WTM = BM/2, WTN = BN/2;
    constexpr int FRM = BM/32, FRN = BN/32;
    __shared__ ushort As[BM][32];
    __shared__ ushort Bs[BN][32];

    int id = blockIdx.x;
    int swz = (id & 7) * (gridDim.x >> 3) + (id >> 3);   // XCD-contiguous chunks
    int bx, by;
    if (CMAJ) { bx = swz / gy; by = swz - bx * gy; }
    else      { by = swz / gx; bx = swz - by * gx; }
    int bm = by * BM, bn = bx * BN;

    int tid = threadIdx.x;
    int lane = tid & 63, wid = tid >> 6;
    int wr = wid >> 1, wc = wid & 1;
    int lrow = lane >> 2;
    int lcol = (lane & 3) * 8;
    int fr = lane & 15, fc = lane >> 4;

    f32x4 acc[FRM][FRN];
#pragma unroll
    for (int i = 0; i < FRM; i++)
#pragma unroll
        for (int j = 0; j < FRN; j++)
#pragma unroll
            for (int r = 0; r < 4; r++) acc[i][j][r] = 0.f;

    for (int k0 = 0; k0 < K; k0 += 32) {
#pragma unroll
        for (int i = 0; i < BM/64; i++) {
            int rt = wid*(BM/4) + i*16;
            load_lds16(A + (size_t)(bm + rt + lrow)*K + k0 + lcol, &As[rt][0]);
        }
#pragma unroll
        for (int i = 0; i < BN/64; i++) {
            int rt = wid*(BN/4) + i*16;
            load_lds16(BT + (size_t)(bn + rt + lrow)*K + k0 + lcol, &Bs[rt][0]);
        }
        asm volatile("s_waitcnt vmcnt(0)" ::: "memory");
        __syncthreads();
        bf16x8 af[FRM], bf[FRN];
#pragma unroll
        for (int mi = 0; mi < FRM; mi++) af[mi] = *(const bf16x8*)&As[wr*WTM + mi*16 + fr][fc*8];
#pragma unroll
        for (int ni = 0; ni < FRN; ni++) bf[ni] = *(const bf16x8*)&Bs[wc*WTN + ni*16 + fr][fc*8];
#pragma unroll
        for (int mi = 0; mi < FRM; mi++)
#pragma unroll
            for (int ni = 0; ni < FRN; ni++)
                acc[mi][ni] = __builtin_amdgcn_mfma_f32_16x16x32_bf16(af[mi], bf[ni], acc[mi][ni], 0, 0, 0);
        __syncthreads();
    }
#pragma unroll
    for (int mi = 0; mi < FRM; mi++) {
#pragma unroll
        for (int r = 0; r < 4; r++) {
            int row = bm + wr*WTM + mi*16 + fc*4 + r;
#pragma unroll
            for (int ni = 0; ni < FRN; ni++) {
                int col = bn + wc*WTN + ni*16 + fr;
                float v = acc[mi][ni][r];
                if (HASB) v += bias[col];
                if (RESID) v += X[(size_t)row * N + col];
                if (RELU) v = fmaxf(v, 0.f);
                storeOut(&C[(size_t)row * N + col], v);
            }
        }
    }
}

// ---------------- flash attention: MFMA, online softmax ----------------
__global__ __launch_bounds__(256) void attn_mfma(const float* __restrict__ qkv,
                                                 __hip_bfloat16* __restrict__ y) {
    const int bx = blockIdx.x;
    const int qt = 15 - (bx & 15);           // heavy tiles first
    const int h  = (bx >> 4) % NH;
    const int b  = bx / (16*NH);
    const int tid  = threadIdx.x;
    const int lane = tid & 63, w = tid >> 6;
    const int fr = lane & 15, fc = lane >> 4;

    __shared__ ushort Qs[64][72];
    __shared__ ushort Ks[64][72];
    __shared__ ushort Vs[64][72];
    __shared__ ushort Ps[4][16][72];

    const int q0 = qt * 64;
    const int srow = tid >> 2, sfs = tid & 3;

    {
        const float* src = qkv + (size_t)(b*SS + q0 + srow)*QKVN + h*HD;
#pragma unroll
        for (int it = 0; it < 4; it++) {
            int d0 = sfs*4 + it*16;
            float4 v4 = *(const float4*)(src + d0);
            ushort4 u;
            u.x = f2bs(v4.x); u.y = f2bs(v4.y); u.z = f2bs(v4.z); u.w = f2bs(v4.w);
            *(ushort4*)&Qs[srow][d0] = u;
        }
    }
    bf16x8 qf[2];
#pragma unroll
    for (int s = 0; s < 2; s++) qf[s] = *(const bf16x8*)&Qs[w*16 + fr][s*32 + fc*8];

    f32x4 oacc[4];
#pragma unroll
    for (int ni = 0; ni < 4; ni++)
#pragma unroll
        for (int r = 0; r < 4; r++) oacc[ni][r] = 0.f;
    float m[4] = {-INFINITY, -INFINITY, -INFINITY, -INFINITY};
    float l[4] = {0.f, 0.f, 0.f, 0.f};

    for (int kt = 0; kt <= qt; kt++) {
        const int kv0 = kt * 64;
        __syncthreads();
        {
            const float* ksrc = qkv + (size_t)(b*SS + kv0 + srow)*QKVN + D   + h*HD;
            const float* vsrc = qkv + (size_t)(b*SS + kv0 + srow)*QKVN + 2*D + h*HD;
#pragma unroll
            for (int it = 0; it < 4; it++) {
                int d0 = sfs*4 + it*16;
                float4 kv4 = *(const float4*)(ksrc + d0);
                ushort4 u;
                u.x = f2bs(kv4.x); u.y = f2bs(kv4.y); u.z = f2bs(kv4.z); u.w = f2bs(kv4.w);
                *(ushort4*)&Ks[srow][d0] = u;
                float4 vv4 = *(const float4*)(vsrc + d0);
                Vs[d0+0][srow] = f2bs(vv4.x);
                Vs[d0+1][srow] = f2bs(vv4.y);
                Vs[d0+2][srow] = f2bs(vv4.z);
                Vs[d0+3][srow] = f2bs(vv4.w);
            }
        }
        __syncthreads();
        f32x4 sacc[4];
#pragma unroll
        for (int ni = 0; ni < 4; ni++)
#pragma unroll
            for (int r = 0; r < 4; r++) sacc[ni][r] = 0.f;
#pragma unroll
        for (int ni = 0; ni < 4; ni++)
#pragma unroll
            for (int s = 0; s < 2; s++) {
                bf16x8 kf = *(const bf16x8*)&Ks[ni*16 + fr][s*32 + fc*8];
                sacc[ni] = __builtin_amdgcn_mfma_f32_16x16x32_bf16(qf[s], kf, sacc[ni], 0, 0, 0);
            }
        if (kt == qt) {
#pragma unroll
            for (int ni = 0; ni < 4; ni++)
#pragma unroll
                for (int r = 0; r < 4; r++) {
                    float v = sacc[ni][r] * 0.125f;
                    sacc[ni][r] = (ni*16 + fr > w*16 + fc*4 + r) ? -INFINITY : v;
                }
        } else {
#pragma unroll
            for (int ni = 0; ni < 4; ni++)
#pragma unroll
                for (int r = 0; r < 4; r++) sacc[ni][r] *= 0.125f;
        }
        float p[4][4];
#pragma unroll
        for (int r = 0; r < 4; r++) {
            float mx = fmaxf(fmaxf(sacc[0][r], sacc[1][r]), fmaxf(sacc[2][r], sacc[3][r]));
#pragma unroll
            for (int o = 1; o < 16; o <<= 1) mx = fmaxf(mx, __shfl_xor(mx, o, 64));
            float mn = fmaxf(m[r], mx);
            float fac = __expf(m[r] - mn);
            float rs = 0.f;
#pragma unroll
            for (int ni = 0; ni < 4; ni++) {
                float pv = __expf(sacc[ni][r] - mn);
                p[ni][r] = pv;
                rs += pv;
            }
#pragma unroll
            for (int o = 1; o < 16; o <<= 1) rs += __shfl_xor(rs, o, 64);
            l[r] = l[r] * fac + rs;
            m[r] = mn;
#pragma unroll
            for (int ni = 0; ni < 4; ni++) oacc[ni][r] *= fac;
        }
#pragma unroll
        for (int ni = 0; ni < 4; ni++)
#pragma unroll
            for (int r = 0; r < 4; r++)
                Ps[w][fc*4 + r][ni*16 + fr] = f2bs(p[ni][r]);
        bf16x8 pa[2];
#pragma unroll
        for (int s = 0; s < 2; s++) pa[s] = *(const bf16x8*)&Ps[w][fr][s*32 + fc*8];
#pragma unroll
        for (int ni = 0; ni < 4; ni++)
#pragma unroll
            for (int s = 0; s < 2; s++) {
                bf16x8 vf = *(const bf16x8*)&Vs[ni*16 + fr][s*32 + fc*8];
                oacc[ni] = __builtin_amdgcn_mfma_f32_16x16x32_bf16(pa[s], vf, oacc[ni], 0, 0, 0);
            }
    }
#pragma unroll
    for (int r = 0; r < 4; r++) {
        float rinv = 1.f / l[r];
        int row = b*SS + q0 + w*16 + fc*4 + r;
#pragma unroll
        for (int ni = 0; ni < 4; ni++)
            y[(size_t)row*D + h*HD + ni*16 + fr] = __float2bfloat16(oacc[ni][r] * rinv);
    }
}

extern "C" void kernel_launch(void* const* d_in, const int* in_sizes, int n_in,
                              void* d_out, int out_size, void* d_ws, size_t ws_size,
                              hipStream_t stream) {
    const int*   idx  = (const int*)d_in[0];
    const float* tok  = (const float*)d_in[1];
    const float* pos  = (const float*)d_in[2];
    const float* ln1w = (const float*)d_in[3];
    const float* ln1b = (const float*)d_in[4];
    const float* Wq   = (const float*)d_in[5];
    const float* bq   = (const float*)d_in[6];
    const float* Wk   = (const float*)d_in[7];
    const float* bk   = (const float*)d_in[8];
    const float* Wv   = (const float*)d_in[9];
    const float* bv   = (const float*)d_in[10];
    const float* Wo   = (const float*)d_in[11];
    const float* bo   = (const float*)d_in[12];
    const float* ln2w = (const float*)d_in[13];
    const float* ln2b = (const float*)d_in[14];
    const float* W1   = (const float*)d_in[15];
    const float* b1   = (const float*)d_in[16];
    const float* W2   = (const float*)d_in[17];
    const float* b2   = (const float*)d_in[18];
    const float* lnfw = (const float*)d_in[19];
    const float* lnfb = (const float*)d_in[20];
    const float* lmw  = (const float*)d_in[21];
    float* out = (float*)d_out;

    // ---- workspace carve ----
    char* p = (char*)d_ws;
    __hip_bfloat16* qkvT = (__hip_bfloat16*)p; p += (size_t)NL*QKVN*D*2;
    __hip_bfloat16* WoT  = (__hip_bfloat16*)p; p += (size_t)NL*D*D*2;
    __hip_bfloat16* W1T  = (__hip_bfloat16*)p; p += (size_t)NL*DFF*D*2;
    __hip_bfloat16* W2T  = (__hip_bfloat16*)p; p += (size_t)NL*D*DFF*2;
    __hip_bfloat16* lmT  = (__hip_bfloat16*)p; p += (size_t)VOCAB*D*2;
    float*          bqkv = (float*)p;          p += (size_t)NL*QKVN*4;
    float*          x    = (float*)p;          p += (size_t)NROWS*D*4;
    __hip_bfloat16* h    = (__hip_bfloat16*)p; p += (size_t)NROWS*D*2;
    float*          qkv  = (float*)p;          p += (size_t)NROWS*QKVN*4;
    __hip_bfloat16* yb   = (__hip_bfloat16*)p; p += (size_t)NROWS*D*2;
    __hip_bfloat16* a1   = (__hip_bfloat16*)p; p += (size_t)NROWS*DFF*2;

    // ---- weight conversion / transposition ----
    dim3 tDD(D/32, D/32, NL);
    transpose_cvt<<<tDD, 256, 0, stream>>>(Wq, qkvT, D, D, (size_t)D*D, (size_t)QKVN*D, 0);
    transpose_cvt<<<tDD, 256, 0, stream>>>(Wk, qkvT, D, D, (size_t)D*D, (size_t)QKVN*D, D);
    transpose_cvt<<<tDD, 256, 0, stream>>>(Wv, qkvT, D, D, (size_t)D*D, (size_t)QKVN*D, 2*D);
    transpose_cvt<<<tDD, 256, 0, stream>>>(Wo, WoT, D, D, (size_t)D*D, (size_t)D*D, 0);
    transpose_cvt<<<dim3(D/32, DFF/32, NL), 256, 0, stream>>>(W1, W1T, D, DFF, (size_t)D*DFF, (size_t)DFF*D, 0);
    transpose_cvt<<<dim3(DFF/32, D/32, NL), 256, 0, stream>>>(W2, W2T, DFF, D, (size_t)DFF*D, (size_t)D*DFF, 0);
    transpose_cvt<<<dim3(D/32, VOCAB/32, 1), 256, 0, stream>>>(lmw, lmT, D, VOCAB, 0, 0, 0);
    pack_qkv_bias<<<dim3(3, NL), 256, 0, stream>>>(bq, bk, bv, bqkv);

    embed_kernel<<<NROWS, 256, 0, stream>>>(idx, tok, pos, x);

    for (int l = 0; l < NL; l++) {
        layernorm_kernel<<<NROWS, 256, 0, stream>>>(x, ln1w + l*D, ln1b + l*D, h);
        // QKV: M=2048, N=2304, K=768 — 128x64 tiles -> 576 blocks
        gemm_mfma<128,64,0,float,0,0,1><<<576, 256, 0, stream>>>(
            (const ushort*)h, (const ushort*)(qkvT + (size_t)l*QKVN*D),
            bqkv + (size_t)l*QKVN, nullptr, qkv, QKVN, D, QKVN/64, NROWS/128);
        attn_mfma<<<BB*NH*(SS/64), 256, 0, stream>>>(qkv, yb);
        // Wo: N=768, K=768 — 64x64 tiles -> 384 blocks
        gemm_mfma<64,64,0,float,0,1,1><<<384, 256, 0, stream>>>(
            (const ushort*)yb, (const ushort*)(WoT + (size_t)l*D*D),
            bo + (size_t)l*D, x, x, D, D, D/64, NROWS/64);
        layernorm_kernel<<<NROWS, 256, 0, stream>>>(x, ln2w + l*D, ln2b + l*D, h);
        // W1: N=3072, K=768 — 128x128 tiles -> 384 blocks
        gemm_mfma<128,128,0,__hip_bfloat16,1,0,1><<<384, 256, 0, stream>>>(
            (const ushort*)h, (const ushort*)(W1T + (size_t)l*DFF*D),
            b1 + (size_t)l*DFF, nullptr, a1, DFF, D, DFF/128, NROWS/128);
        // W2: N=768, K=3072 — 64x64 tiles -> 384 blocks
        gemm_mfma<64,64,0,float,0,1,1><<<384, 256, 0, stream>>>(
            (const ushort*)a1, (const ushort*)(W2T + (size_t)l*D*DFF),
            b2 + (size_t)l*D, x, x, D, DFF, D/64, NROWS/64);
    }
    layernorm_kernel<<<NROWS, 256, 0, stream>>>(x, lnfw, lnfb, h);
    // lm_head: N=32000, K=768 — 128x128 -> 4000 blocks, CMAJ (N-slice per XCD)
    gemm_mfma<128,128,1,float,0,0,0><<<4000, 256, 0, stream>>>(
        (const ushort*)h, (const ushort*)lmT, nullptr, nullptr, out, VOCAB, D,
        VOCAB/128, NROWS/128);
}

// Round 5
// 1276.976 us; speedup vs baseline: 6.7501x; 1.1028x over previous
//
#include <hip/hip_runtime.h>
#include <hip/hip_bf16.h>
#include <math.h>

#define D 768
#define NH 12
#define HD 64
#define NL 6
#define DFF 3072
#define BB 2
#define SS 1024
#define NROWS (BB*SS)   // 2048
#define VOCAB 32000
#define QKVN (3*D)      // 2304
#define LN_EPS 1e-5f

typedef __attribute__((ext_vector_type(8))) short bf16x8;
typedef __attribute__((ext_vector_type(4))) float f32x4;

typedef __attribute__((address_space(1))) const unsigned char* gas_ptr;
typedef __attribute__((address_space(3))) unsigned char* las_ptr;

__device__ __forceinline__ void load_lds16(const void* g, void* l) {
    __builtin_amdgcn_global_load_lds((gas_ptr)g, (las_ptr)l, 16, 0, 0);
}

__device__ __forceinline__ void storeOut(float* p, float v) { *p = v; }
__device__ __forceinline__ void storeOut(__hip_bfloat16* p, float v) { *p = __float2bfloat16(v); }
__device__ __forceinline__ ushort f2bs(float f) {
    __hip_bfloat16 h = __float2bfloat16(f);
    return *(ushort*)&h;
}

// ---------------- embedding ----------------
__global__ void embed_kernel(const int* __restrict__ idx, const float* __restrict__ tok,
                             const float* __restrict__ pos, float* __restrict__ x) {
    int row = blockIdx.x;
    int s = row % SS;
    int t = idx[row];
    for (int c = threadIdx.x; c < D; c += blockDim.x)
        x[row*D + c] = tok[(size_t)t*D + c] + pos[s*D + c];
}

// ---------------- layernorm (row of 768), templated output ----------------
template<typename OT>
__global__ __launch_bounds__(256) void layernorm_kernel(const float* __restrict__ x,
                                                        const float* __restrict__ w,
                                                        const float* __restrict__ b,
                                                        OT* __restrict__ out) {
    int row = blockIdx.x;
    __shared__ float l1[4], l2[4];
    int base = row * D;
    float vals[3];
    float s1 = 0.f, s2 = 0.f;
#pragma unroll
    for (int i = 0; i < 3; i++) {
        float v = x[base + threadIdx.x + i*256];
        vals[i] = v; s1 += v; s2 += v*v;
    }
#pragma unroll
    for (int o = 32; o > 0; o >>= 1) {
        s1 += __shfl_down(s1, o, 64);
        s2 += __shfl_down(s2, o, 64);
    }
    if ((threadIdx.x & 63) == 0) { l1[threadIdx.x >> 6] = s1; l2[threadIdx.x >> 6] = s2; }
    __syncthreads();
    float sum   = l1[0] + l1[1] + l1[2] + l1[3];
    float sumsq = l2[0] + l2[1] + l2[2] + l2[3];
    float mu  = sum * (1.f / D);
    float var = sumsq * (1.f / D) - mu * mu;
    float inv = rsqrtf(var + LN_EPS);
#pragma unroll
    for (int i = 0; i < 3; i++) {
        int c = threadIdx.x + i*256;
        storeOut(&out[base + c], (vals[i] - mu) * inv * w[c] + b[c]);
    }
}

// ---------------- transpose + fp32->bf16: src [K,N] -> dst [N,K] ----------------
__global__ __launch_bounds__(256) void transpose_cvt(const float* __restrict__ src,
                                                     __hip_bfloat16* __restrict__ dst,
                                                     int K, int N,
                                                     size_t srcLayerStride, size_t dstLayerStride,
                                                     int dstRowOff) {
    int l = blockIdx.z;
    src += (size_t)l * srcLayerStride;
    dst += (size_t)l * dstLayerStride + (size_t)dstRowOff * K;
    __shared__ float t[32][33];
    int k0 = blockIdx.x*32, n0 = blockIdx.y*32;
    int tx = threadIdx.x & 31, ty = threadIdx.x >> 5;   // 32x8
    for (int i = ty; i < 32; i += 8) t[i][tx] = src[(size_t)(k0+i)*N + n0+tx];
    __syncthreads();
    for (int i = ty; i < 32; i += 8) dst[(size_t)(n0+i)*K + k0+tx] = __float2bfloat16(t[tx][i]);
}

// ---------------- per-layer V^T extraction (bf16): qkv[.,2D+h*64+d] -> vt[bh][d][s] ----------------
__global__ __launch_bounds__(256) void vtrans_kernel(const ushort* __restrict__ qkv,
                                                     ushort* __restrict__ vt) {
    int bh = blockIdx.z;           // b*NH+h
    int st = blockIdx.y;           // s tile (32)
    int dt = blockIdx.x;           // d tile (2)
    __shared__ ushort t[32][33];
    int tx = threadIdx.x & 31, ty = threadIdx.x >> 5;
    int b = bh / NH, h = bh % NH;
    int s0 = st*32, d0 = dt*32;
    for (int i = ty; i < 32; i += 8)
        t[i][tx] = qkv[(size_t)(b*SS + s0+i)*QKVN + 2*D + h*HD + d0 + tx];
    __syncthreads();
    for (int i = ty; i < 32; i += 8)
        vt[((size_t)bh*HD + d0+i)*SS + s0 + tx] = t[tx][i];
}

// ---------------- pack qkv bias ----------------
__global__ void pack_qkv_bias(const float* __restrict__ bq, const float* __restrict__ bk,
                              const float* __restrict__ bv, float* __restrict__ dst) {
    int l = blockIdx.y;
    int i = blockIdx.x*256 + threadIdx.x;   // 0..767
    dst[l*QKVN + i]         = bq[l*D + i];
    dst[l*QKVN + D + i]     = bk[l*D + i];
    dst[l*QKVN + 2*D + i]   = bv[l*D + i];
}

// ---------------- bf16 MFMA GEMM, templated tile; XOR-swizzled LDS ----------------
// 1D grid (nwg % 8 == 0), XCD-bijective swizzle; CMAJ=1 walks M fastest.
// LDS rows are 64B (4x16B chunks); chunk c of row r stored at c^(r&3) — the
// global SOURCE is inverse-permuted (same XOR) so global_load_lds' linear
// dest lands data where the swizzled ds_read expects it (rule #21).
template<int BM, int BN, int CMAJ, typename OT, int RELU, int RESID, int HASB>
__global__ __launch_bounds__(256) void gemm_mfma(const ushort* __restrict__ A,
                                                 const ushort* __restrict__ BT,
                                                 const float* __restrict__ bias,
                                                 const float* __restrict__ X,
                                                 OT* __restrict__ C,
                                                 int N, int K, int gx, int gy) {
    constexpr int WTM = BM/2, WTN = BN/2;
    constexpr int FRM = BM/32, FRN = BN/32;
    __shared__ ushort As[BM][32];
    __shared__ ushort Bs[BN][32];

    int id = blockIdx.x;
    int swz = (id & 7) * (gridDim.x >> 3) + (id >> 3);
    int bx, by;
    if (CMAJ) { bx = swz / gy; by = swz - bx * gy; }
    else      { by = swz / gx; bx = swz - by * gx; }
    int bm = by * BM, bn = bx * BN;

    int tid = threadIdx.x;
    int lane = tid & 63, wid = tid >> 6;
    int wr = wid >> 1, wc = wid & 1;
    int lrow = lane >> 2;                         // 0..15
    int lcol = (((lane & 3) ^ (lrow & 3)) * 8);   // swizzled source chunk
    int fr = lane & 15, fc = lane >> 4;

    f32x4 acc[FRM][FRN];
#pragma unroll
    for (int i = 0; i < FRM; i++)
#pragma unroll
        for (int j = 0; j < FRN; j++)
#pragma unroll
            for (int r = 0; r < 4; r++) acc[i][j][r] = 0.f;

    for (int k0 = 0; k0 < K; k0 += 32) {
#pragma unroll
        for (int i = 0; i < BM/64; i++) {
            int rt = wid*(BM/4) + i*16;
            load_lds16(A + (size_t)(bm + rt + lrow)*K + k0 + lcol, &As[rt][0]);
        }
#pragma unroll
        for (int i = 0; i < BN/64; i++) {
            int rt = wid*(BN/4) + i*16;
            load_lds16(BT + (size_t)(bn + rt + lrow)*K + k0 + lcol, &Bs[rt][0]);
        }
        asm volatile("s_waitcnt vmcnt(0)" ::: "memory");
        __syncthreads();
        bf16x8 af[FRM], bf[FRN];
#pragma unroll
        for (int mi = 0; mi < FRM; mi++)
            af[mi] = *(const bf16x8*)&As[wr*WTM + mi*16 + fr][(fc ^ (fr & 3))*8];
#pragma unroll
        for (int ni = 0; ni < FRN; ni++)
            bf[ni] = *(const bf16x8*)&Bs[wc*WTN + ni*16 + fr][(fc ^ (fr & 3))*8];
#pragma unroll
        for (int mi = 0; mi < FRM; mi++)
#pragma unroll
            for (int ni = 0; ni < FRN; ni++)
                acc[mi][ni] = __builtin_amdgcn_mfma_f32_16x16x32_bf16(af[mi], bf[ni], acc[mi][ni], 0, 0, 0);
        __syncthreads();
    }
#pragma unroll
    for (int mi = 0; mi < FRM; mi++) {
#pragma unroll
        for (int r = 0; r < 4; r++) {
            int row = bm + wr*WTM + mi*16 + fc*4 + r;
#pragma unroll
            for (int ni = 0; ni < FRN; ni++) {
                int col = bn + wc*WTN + ni*16 + fr;
                float v = acc[mi][ni][r];
                if (HASB) v += bias[col];
                if (RESID) v += X[(size_t)row * N + col];
                if (RELU) v = fmaxf(v, 0.f);
                storeOut(&C[(size_t)row * N + col], v);
            }
        }
    }
}

// ---------------- flash attention: all-bf16, global_load_lds staging ----------------
// qkv: bf16 [2048][2304]; vt: bf16 [B*NH][64][1024] (V^T per head).
// 64-row tiles: 128B rows = 8x16B chunks, chunk c of row r at c^(r&7).
__global__ __launch_bounds__(256) void attn_mfma(const ushort* __restrict__ qkv,
                                                 const ushort* __restrict__ vt,
                                                 __hip_bfloat16* __restrict__ y) {
    const int bx = blockIdx.x;
    const int qt = 15 - (bx & 15);           // heavy tiles first
    const int h  = (bx >> 4) % NH;
    const int b  = bx / (16*NH);
    const int tid  = threadIdx.x;
    const int lane = tid & 63, w = tid >> 6;
    const int fr = lane & 15, fc = lane >> 4;

    __shared__ ushort Qs[64][64];
    __shared__ ushort Ks[64][64];
    __shared__ ushort Vs[64][64];     // V^T tile: [d][kv]
    __shared__ ushort Ps[4][16][72];  // per-wave P strip (VALU-written, padded)

    const int q0 = qt * 64;
    const int srow8  = lane >> 3;                 // 0..7 (row within 8-row chunk)
    const int schunk = (lane & 7) ^ srow8;        // swizzled source chunk

    // ---- stage Q tile (wave-local rows; vmcnt only, no barrier) ----
#pragma unroll
    for (int j = 0; j < 2; j++) {
        int r = w*16 + j*8 + srow8;
        load_lds16(qkv + (size_t)(b*SS + q0 + r)*QKVN + h*HD + schunk*8, &Qs[w*16 + j*8][0]);
    }
    asm volatile("s_waitcnt vmcnt(0)" ::: "memory");
    bf16x8 qf[2];
#pragma unroll
    for (int s = 0; s < 2; s++)
        qf[s] = *(const bf16x8*)&Qs[w*16 + fr][((s*4 + fc) ^ (fr & 7))*8];

    f32x4 oacc[4];
#pragma unroll
    for (int ni = 0; ni < 4; ni++)
#pragma unroll
        for (int r = 0; r < 4; r++) oacc[ni][r] = 0.f;
    float m[4] = {-INFINITY, -INFINITY, -INFINITY, -INFINITY};
    float l[4] = {0.f, 0.f, 0.f, 0.f};

    for (int kt = 0; kt <= qt; kt++) {
        const int kv0 = kt * 64;
        __syncthreads();   // previous iteration's reads done
#pragma unroll
        for (int j = 0; j < 2; j++) {
            int r = w*16 + j*8 + srow8;
            load_lds16(qkv + (size_t)(b*SS + kv0 + r)*QKVN + D + h*HD + schunk*8, &Ks[w*16 + j*8][0]);
            load_lds16(vt + ((size_t)(b*NH + h)*HD + r)*SS + kv0 + schunk*8, &Vs[w*16 + j*8][0]);
        }
        asm volatile("s_waitcnt vmcnt(0)" ::: "memory");
        __syncthreads();
        // ---- S = Q K^T ----
        f32x4 sacc[4];
#pragma unroll
        for (int ni = 0; ni < 4; ni++)
#pragma unroll
            for (int r = 0; r < 4; r++) sacc[ni][r] = 0.f;
#pragma unroll
        for (int ni = 0; ni < 4; ni++)
#pragma unroll
            for (int s = 0; s < 2; s++) {
                bf16x8 kf = *(const bf16x8*)&Ks[ni*16 + fr][((s*4 + fc) ^ (fr & 7))*8];
                sacc[ni] = __builtin_amdgcn_mfma_f32_16x16x32_bf16(qf[s], kf, sacc[ni], 0, 0, 0);
            }
        if (kt == qt) {
#pragma unroll
            for (int ni = 0; ni < 4; ni++)
#pragma unroll
                for (int r = 0; r < 4; r++) {
                    float v = sacc[ni][r] * 0.125f;
                    sacc[ni][r] = (ni*16 + fr > w*16 + fc*4 + r) ? -INFINITY : v;
                }
        } else {
#pragma unroll
            for (int ni = 0; ni < 4; ni++)
#pragma unroll
                for (int r = 0; r < 4; r++) sacc[ni][r] *= 0.125f;
        }
        // ---- online softmax ----
        float p[4][4];
#pragma unroll
        for (int r = 0; r < 4; r++) {
            float mx = fmaxf(fmaxf(sacc[0][r], sacc[1][r]), fmaxf(sacc[2][r], sacc[3][r]));
#pragma unroll
            for (int o = 1; o < 16; o <<= 1) mx = fmaxf(mx, __shfl_xor(mx, o, 64));
            float mn = fmaxf(m[r], mx);
            float fac = __expf(m[r] - mn);
            float rs = 0.f;
#pragma unroll
            for (int ni = 0; ni < 4; ni++) {
                float pv = __expf(sacc[ni][r] - mn);
                p[ni][r] = pv;
                rs += pv;
            }
#pragma unroll
            for (int o = 1; o < 16; o <<= 1) rs += __shfl_xor(rs, o, 64);
            l[r] = l[r] * fac + rs;
            m[r] = mn;
#pragma unroll
            for (int ni = 0; ni < 4; ni++) oacc[ni][r] *= fac;
        }
#pragma unroll
        for (int ni = 0; ni < 4; ni++)
#pragma unroll
            for (int r = 0; r < 4; r++)
                Ps[w][fc*4 + r][ni*16 + fr] = f2bs(p[ni][r]);
        bf16x8 pa[2];
#pragma unroll
        for (int s = 0; s < 2; s++) pa[s] = *(const bf16x8*)&Ps[w][fr][s*32 + fc*8];
#pragma unroll
        for (int ni = 0; ni < 4; ni++)
#pragma unroll
            for (int s = 0; s < 2; s++) {
                bf16x8 vf = *(const bf16x8*)&Vs[ni*16 + fr][((s*4 + fc) ^ (fr & 7))*8];
                oacc[ni] = __builtin_amdgcn_mfma_f32_16x16x32_bf16(pa[s], vf, oacc[ni], 0, 0, 0);
            }
    }
#pragma unroll
    for (int r = 0; r < 4; r++) {
        float rinv = 1.f / l[r];
        int row = b*SS + q0 + w*16 + fc*4 + r;
#pragma unroll
        for (int ni = 0; ni < 4; ni++)
            y[(size_t)row*D + h*HD + ni*16 + fr] = __float2bfloat16(oacc[ni][r] * rinv);
    }
}

extern "C" void kernel_launch(void* const* d_in, const int* in_sizes, int n_in,
                              void* d_out, int out_size, void* d_ws, size_t ws_size,
                              hipStream_t stream) {
    const int*   idx  = (const int*)d_in[0];
    const float* tok  = (const float*)d_in[1];
    const float* pos  = (const float*)d_in[2];
    const float* ln1w = (const float*)d_in[3];
    const float* ln1b = (const float*)d_in[4];
    const float* Wq   = (const float*)d_in[5];
    const float* bq   = (const float*)d_in[6];
    const float* Wk   = (const float*)d_in[7];
    const float* bk   = (const float*)d_in[8];
    const float* Wv   = (const float*)d_in[9];
    const float* bv   = (const float*)d_in[10];
    const float* Wo   = (const float*)d_in[11];
    const float* bo   = (const float*)d_in[12];
    const float* ln2w = (const float*)d_in[13];
    const float* ln2b = (const float*)d_in[14];
    const float* W1   = (const float*)d_in[15];
    const float* b1   = (const float*)d_in[16];
    const float* W2   = (const float*)d_in[17];
    const float* b2   = (const float*)d_in[18];
    const float* lnfw = (const float*)d_in[19];
    const float* lnfb = (const float*)d_in[20];
    const float* lmw  = (const float*)d_in[21];
    float* out = (float*)d_out;

    // ---- workspace carve ----
    char* p = (char*)d_ws;
    __hip_bfloat16* qkvT = (__hip_bfloat16*)p; p += (size_t)NL*QKVN*D*2;
    __hip_bfloat16* WoT  = (__hip_bfloat16*)p; p += (size_t)NL*D*D*2;
    __hip_bfloat16* W1T  = (__hip_bfloat16*)p; p += (size_t)NL*DFF*D*2;
    __hip_bfloat16* W2T  = (__hip_bfloat16*)p; p += (size_t)NL*D*DFF*2;
    __hip_bfloat16* lmT  = (__hip_bfloat16*)p; p += (size_t)VOCAB*D*2;
    float*          bqkv = (float*)p;          p += (size_t)NL*QKVN*4;
    float*          x    = (float*)p;          p += (size_t)NROWS*D*4;
    __hip_bfloat16* h    = (__hip_bfloat16*)p; p += (size_t)NROWS*D*2;
    __hip_bfloat16* qkv  = (__hip_bfloat16*)p; p += (size_t)NROWS*QKVN*2;   // bf16 now
    __hip_bfloat16* vt   = (__hip_bfloat16*)p; p += (size_t)BB*NH*HD*SS*2;  // V^T per head
    __hip_bfloat16* yb   = (__hip_bfloat16*)p; p += (size_t)NROWS*D*2;
    __hip_bfloat16* a1   = (__hip_bfloat16*)p; p += (size_t)NROWS*DFF*2;

    // ---- weight conversion / transposition ----
    dim3 tDD(D/32, D/32, NL);
    transpose_cvt<<<tDD, 256, 0, stream>>>(Wq, qkvT, D, D, (size_t)D*D, (size_t)QKVN*D, 0);
    transpose_cvt<<<tDD, 256, 0, stream>>>(Wk, qkvT, D, D, (size_t)D*D, (size_t)QKVN*D, D);
    transpose_cvt<<<tDD, 256, 0, stream>>>(Wv, qkvT, D, D, (size_t)D*D, (size_t)QKVN*D, 2*D);
    transpose_cvt<<<tDD, 256, 0, stream>>>(Wo, WoT, D, D, (size_t)D*D, (size_t)D*D, 0);
    transpose_cvt<<<dim3(D/32, DFF/32, NL), 256, 0, stream>>>(W1, W1T, D, DFF, (size_t)D*DFF, (size_t)DFF*D, 0);
    transpose_cvt<<<dim3(DFF/32, D/32, NL), 256, 0, stream>>>(W2, W2T, DFF, D, (size_t)DFF*D, (size_t)D*DFF, 0);
    transpose_cvt<<<dim3(D/32, VOCAB/32, 1), 256, 0, stream>>>(lmw, lmT, D, VOCAB, 0, 0, 0);
    pack_qkv_bias<<<dim3(3, NL), 256, 0, stream>>>(bq, bk, bv, bqkv);

    embed_kernel<<<NROWS, 256, 0, stream>>>(idx, tok, pos, x);

    for (int l = 0; l < NL; l++) {
        layernorm_kernel<<<NROWS, 256, 0, stream>>>(x, ln1w + l*D, ln1b + l*D, h);
        // QKV: M=2048, N=2304, K=768 — 128x64 tiles -> 576 blocks, bf16 out
        gemm_mfma<128,64,0,__hip_bfloat16,0,0,1><<<576, 256, 0, stream>>>(
            (const ushort*)h, (const ushort*)(qkvT + (size_t)l*QKVN*D),
            bqkv + (size_t)l*QKVN, nullptr, qkv, QKVN, D, QKVN/64, NROWS/128);
        vtrans_kernel<<<dim3(2, SS/32, BB*NH), 256, 0, stream>>>((const ushort*)qkv, (ushort*)vt);
        attn_mfma<<<BB*NH*(SS/64), 256, 0, stream>>>((const ushort*)qkv, (const ushort*)vt, yb);
        // Wo: N=768, K=768 — 64x64 tiles -> 384 blocks
        gemm_mfma<64,64,0,float,0,1,1><<<384, 256, 0, stream>>>(
            (const ushort*)yb, (const ushort*)(WoT + (size_t)l*D*D),
            bo + (size_t)l*D, x, x, D, D, D/64, NROWS/64);
        layernorm_kernel<<<NROWS, 256, 0, stream>>>(x, ln2w + l*D, ln2b + l*D, h);
        // W1: N=3072, K=768 — 128x128 tiles -> 384 blocks
        gemm_mfma<128,128,0,__hip_bfloat16,1,0,1><<<384, 256, 0, stream>>>(
            (const ushort*)h, (const ushort*)(W1T + (size_t)l*DFF*D),
            b1 + (size_t)l*DFF, nullptr, a1, DFF, D, DFF/128, NROWS/128);
        // W2: N=768, K=3072 — 64x64 tiles -> 384 blocks
        gemm_mfma<64,64,0,float,0,1,1><<<384, 256, 0, stream>>>(
            (const ushort*)a1, (const ushort*)(W2T + (size_t)l*D*DFF),
            b2 + (size_t)l*D, x, x, D, DFF, D/64, NROWS/64);
    }
    layernorm_kernel<<<NROWS, 256, 0, stream>>>(x, lnfw, lnfb, h);
    // lm_head: N=32000, K=768 — 128x128 -> 4000 blocks, CMAJ (N-slice per XCD)
    gemm_mfma<128,128,1,float,0,0,0><<<4000, 256, 0, stream>>>(
        (const ushort*)h, (const ushort*)lmT, nullptr, nullptr, out, VOCAB, D,
        VOCAB/128, NROWS/128);
}

// Round 6
// 1246.269 us; speedup vs baseline: 6.9164x; 1.0246x over previous
//
#include <hip/hip_runtime.h>
#include <hip/hip_bf16.h>
#include <math.h>

#define D 768
#define NH 12
#define HD 64
#define NL 6
#define DFF 3072
#define BB 2
#define SS 1024
#define NROWS (BB*SS)   // 2048
#define VOCAB 32000
#define QKVN (3*D)      // 2304
#define LN_EPS 1e-5f

typedef __attribute__((ext_vector_type(8))) short bf16x8;
typedef __attribute__((ext_vector_type(4))) float f32x4;

typedef __attribute__((address_space(1))) const unsigned char* gas_ptr;
typedef __attribute__((address_space(3))) unsigned char* las_ptr;

__device__ __forceinline__ void load_lds16(const void* g, void* l) {
    __builtin_amdgcn_global_load_lds((gas_ptr)g, (las_ptr)l, 16, 0, 0);
}

__device__ __forceinline__ void storeOut(float* p, float v) { *p = v; }
__device__ __forceinline__ void storeOut(__hip_bfloat16* p, float v) { *p = __float2bfloat16(v); }
__device__ __forceinline__ ushort f2bs(float f) {
    __hip_bfloat16 h = __float2bfloat16(f);
    return *(ushort*)&h;
}

// ---------------- embedding ----------------
__global__ void embed_kernel(const int* __restrict__ idx, const float* __restrict__ tok,
                             const float* __restrict__ pos, float* __restrict__ x) {
    int row = blockIdx.x;
    int s = row % SS;
    int t = idx[row];
    for (int c = threadIdx.x; c < D; c += blockDim.x)
        x[row*D + c] = tok[(size_t)t*D + c] + pos[s*D + c];
}

// ---------------- layernorm (row of 768), templated output ----------------
template<typename OT>
__global__ __launch_bounds__(256) void layernorm_kernel(const float* __restrict__ x,
                                                        const float* __restrict__ w,
                                                        const float* __restrict__ b,
                                                        OT* __restrict__ out) {
    int row = blockIdx.x;
    __shared__ float l1[4], l2[4];
    int base = row * D;
    float vals[3];
    float s1 = 0.f, s2 = 0.f;
#pragma unroll
    for (int i = 0; i < 3; i++) {
        float v = x[base + threadIdx.x + i*256];
        vals[i] = v; s1 += v; s2 += v*v;
    }
#pragma unroll
    for (int o = 32; o > 0; o >>= 1) {
        s1 += __shfl_down(s1, o, 64);
        s2 += __shfl_down(s2, o, 64);
    }
    if ((threadIdx.x & 63) == 0) { l1[threadIdx.x >> 6] = s1; l2[threadIdx.x >> 6] = s2; }
    __syncthreads();
    float sum   = l1[0] + l1[1] + l1[2] + l1[3];
    float sumsq = l2[0] + l2[1] + l2[2] + l2[3];
    float mu  = sum * (1.f / D);
    float var = sumsq * (1.f / D) - mu * mu;
    float inv = rsqrtf(var + LN_EPS);
#pragma unroll
    for (int i = 0; i < 3; i++) {
        int c = threadIdx.x + i*256;
        storeOut(&out[base + c], (vals[i] - mu) * inv * w[c] + b[c]);
    }
}

// ---------------- transpose + fp32->bf16: src [K,N] -> dst [N,K] ----------------
__global__ __launch_bounds__(256) void transpose_cvt(const float* __restrict__ src,
                                                     __hip_bfloat16* __restrict__ dst,
                                                     int K, int N,
                                                     size_t srcLayerStride, size_t dstLayerStride,
                                                     int dstRowOff) {
    int l = blockIdx.z;
    src += (size_t)l * srcLayerStride;
    dst += (size_t)l * dstLayerStride + (size_t)dstRowOff * K;
    __shared__ float t[32][33];
    int k0 = blockIdx.x*32, n0 = blockIdx.y*32;
    int tx = threadIdx.x & 31, ty = threadIdx.x >> 5;   // 32x8
    for (int i = ty; i < 32; i += 8) t[i][tx] = src[(size_t)(k0+i)*N + n0+tx];
    __syncthreads();
    for (int i = ty; i < 32; i += 8) dst[(size_t)(n0+i)*K + k0+tx] = __float2bfloat16(t[tx][i]);
}

// ---------------- per-layer V^T extraction ----------------
__global__ __launch_bounds__(256) void vtrans_kernel(const ushort* __restrict__ qkv,
                                                     ushort* __restrict__ vt) {
    int bh = blockIdx.z;
    int st = blockIdx.y;
    int dt = blockIdx.x;
    __shared__ ushort t[32][33];
    int tx = threadIdx.x & 31, ty = threadIdx.x >> 5;
    int b = bh / NH, h = bh % NH;
    int s0 = st*32, d0 = dt*32;
    for (int i = ty; i < 32; i += 8)
        t[i][tx] = qkv[(size_t)(b*SS + s0+i)*QKVN + 2*D + h*HD + d0 + tx];
    __syncthreads();
    for (int i = ty; i < 32; i += 8)
        vt[((size_t)bh*HD + d0+i)*SS + s0 + tx] = t[tx][i];
}

// ---------------- pack qkv bias ----------------
__global__ void pack_qkv_bias(const float* __restrict__ bq, const float* __restrict__ bk,
                              const float* __restrict__ bv, float* __restrict__ dst) {
    int l = blockIdx.y;
    int i = blockIdx.x*256 + threadIdx.x;
    dst[l*QKVN + i]         = bq[l*D + i];
    dst[l*QKVN + D + i]     = bk[l*D + i];
    dst[l*QKVN + 2*D + i]   = bv[l*D + i];
}

// ---------------- bf16 MFMA GEMM — min-2-phase double-buffered pipeline ----------------
// Stage tile t+1 (global_load_lds) BEFORE computing tile t; one vmcnt(0)+barrier
// per K-step (stage latency hides under ds_read+MFMA). XCD-bijective 1D swizzle.
#define GSTAGE(buf, k0) do {                                                     \
    _Pragma("unroll")                                                            \
    for (int i_ = 0; i_ < BM/64; i_++) {                                         \
        int rt_ = wid*(BM/4) + i_*16;                                            \
        load_lds16(A + (size_t)(bm + rt_ + lrow)*K + (k0) + lcol,                \
                   &As[buf][rt_][0]);                                            \
    }                                                                            \
    _Pragma("unroll")                                                            \
    for (int i_ = 0; i_ < BN/64; i_++) {                                         \
        int rt_ = wid*(BN/4) + i_*16;                                            \
        load_lds16(BT + (size_t)(bn + rt_ + lrow)*K + (k0) + lcol,               \
                   &Bs[buf][rt_][0]);                                            \
    } } while (0)

template<int BM, int BN, int CMAJ, typename OT, int RELU, int RESID, int HASB>
__global__ __launch_bounds__(256) void gemm_mfma(const ushort* __restrict__ A,
                                                 const ushort* __restrict__ BT,
                                                 const float* __restrict__ bias,
                                                 const float* __restrict__ X,
                                                 OT* __restrict__ C,
                                                 int N, int K, int gx, int gy) {
    constexpr int WTM = BM/2, WTN = BN/2;
    constexpr int FRM = BM/32, FRN = BN/32;
    __shared__ ushort As[2][BM][32];
    __shared__ ushort Bs[2][BN][32];

    int id = blockIdx.x;
    int swz = (id & 7) * (gridDim.x >> 3) + (id >> 3);
    int bx, by;
    if (CMAJ) { bx = swz / gy; by = swz - bx * gy; }
    else      { by = swz / gx; bx = swz - by * gx; }
    int bm = by * BM, bn = bx * BN;

    int tid = threadIdx.x;
    int lane = tid & 63, wid = tid >> 6;
    int wr = wid >> 1, wc = wid & 1;
    int lrow = lane >> 2;
    int lcol = (((lane & 3) ^ (lrow & 3)) * 8);
    int fr = lane & 15, fc = lane >> 4;

    f32x4 acc[FRM][FRN];
#pragma unroll
    for (int i = 0; i < FRM; i++)
#pragma unroll
        for (int j = 0; j < FRN; j++)
#pragma unroll
            for (int r = 0; r < 4; r++) acc[i][j][r] = 0.f;

    GSTAGE(0, 0);
    asm volatile("s_waitcnt vmcnt(0)" ::: "memory");
    __syncthreads();

    int cur = 0;
    for (int t = 0; t < K/32; t++) {
        if (t*32 + 32 < K) GSTAGE(cur^1, t*32 + 32);
        bf16x8 af[FRM], bf[FRN];
#pragma unroll
        for (int mi = 0; mi < FRM; mi++)
            af[mi] = *(const bf16x8*)&As[cur][wr*WTM + mi*16 + fr][(fc ^ (fr & 3))*8];
#pragma unroll
        for (int ni = 0; ni < FRN; ni++)
            bf[ni] = *(const bf16x8*)&Bs[cur][wc*WTN + ni*16 + fr][(fc ^ (fr & 3))*8];
        __builtin_amdgcn_s_setprio(1);
#pragma unroll
        for (int mi = 0; mi < FRM; mi++)
#pragma unroll
            for (int ni = 0; ni < FRN; ni++)
                acc[mi][ni] = __builtin_amdgcn_mfma_f32_16x16x32_bf16(af[mi], bf[ni], acc[mi][ni], 0, 0, 0);
        __builtin_amdgcn_s_setprio(0);
        asm volatile("s_waitcnt vmcnt(0)" ::: "memory");
        __syncthreads();
        cur ^= 1;
    }
#pragma unroll
    for (int mi = 0; mi < FRM; mi++) {
#pragma unroll
        for (int r = 0; r < 4; r++) {
            int row = bm + wr*WTM + mi*16 + fc*4 + r;
#pragma unroll
            for (int ni = 0; ni < FRN; ni++) {
                int col = bn + wc*WTN + ni*16 + fr;
                float v = acc[mi][ni][r];
                if (HASB) v += bias[col];
                if (RESID) v += X[(size_t)row * N + col];
                if (RELU) v = fmaxf(v, 0.f);
                storeOut(&C[(size_t)row * N + col], v);
            }
        }
    }
}

// ---------------- flash attention: all-bf16, dbuf'd K/V staging ----------------
#define KVSTAGE(buf, kv0) do {                                                   \
    _Pragma("unroll")                                                            \
    for (int j_ = 0; j_ < 2; j_++) {                                             \
        int r_ = w*16 + j_*8 + srow8;                                            \
        load_lds16(qkv + (size_t)(b*SS + (kv0) + r_)*QKVN + D + h*HD + schunk*8, \
                   &Ks[buf][w*16 + j_*8][0]);                                    \
        load_lds16(vt + ((size_t)(b*NH + h)*HD + r_)*SS + (kv0) + schunk*8,      \
                   &Vs[buf][w*16 + j_*8][0]);                                    \
    } } while (0)

__global__ __launch_bounds__(256) void attn_mfma(const ushort* __restrict__ qkv,
                                                 const ushort* __restrict__ vt,
                                                 __hip_bfloat16* __restrict__ y) {
    const int bx = blockIdx.x;
    const int qt = 15 - (bx & 15);           // heavy tiles first
    const int h  = (bx >> 4) % NH;
    const int b  = bx / (16*NH);
    const int tid  = threadIdx.x;
    const int lane = tid & 63, w = tid >> 6;
    const int fr = lane & 15, fc = lane >> 4;

    __shared__ ushort Qs[64][64];
    __shared__ ushort Ks[2][64][64];
    __shared__ ushort Vs[2][64][64];
    __shared__ ushort Ps[4][16][72];

    const int q0 = qt * 64;
    const int srow8  = lane >> 3;
    const int schunk = (lane & 7) ^ srow8;

    // ---- stage Q tile + prologue K/V tile ----
#pragma unroll
    for (int j = 0; j < 2; j++) {
        int r = w*16 + j*8 + srow8;
        load_lds16(qkv + (size_t)(b*SS + q0 + r)*QKVN + h*HD + schunk*8, &Qs[w*16 + j*8][0]);
    }
    KVSTAGE(0, 0);
    asm volatile("s_waitcnt vmcnt(0)" ::: "memory");
    __syncthreads();
    bf16x8 qf[2];
#pragma unroll
    for (int s = 0; s < 2; s++)
        qf[s] = *(const bf16x8*)&Qs[w*16 + fr][((s*4 + fc) ^ (fr & 7))*8];

    f32x4 oacc[4];
#pragma unroll
    for (int ni = 0; ni < 4; ni++)
#pragma unroll
        for (int r = 0; r < 4; r++) oacc[ni][r] = 0.f;
    float m[4] = {-INFINITY, -INFINITY, -INFINITY, -INFINITY};
    float l[4] = {0.f, 0.f, 0.f, 0.f};

    int cur = 0;
    for (int kt = 0; kt <= qt; kt++) {
        if (kt < qt) KVSTAGE(cur^1, (kt+1)*64);
        // ---- S = Q K^T ----
        f32x4 sacc[4];
#pragma unroll
        for (int ni = 0; ni < 4; ni++)
#pragma unroll
            for (int r = 0; r < 4; r++) sacc[ni][r] = 0.f;
#pragma unroll
        for (int ni = 0; ni < 4; ni++)
#pragma unroll
            for (int s = 0; s < 2; s++) {
                bf16x8 kf = *(const bf16x8*)&Ks[cur][ni*16 + fr][((s*4 + fc) ^ (fr & 7))*8];
                sacc[ni] = __builtin_amdgcn_mfma_f32_16x16x32_bf16(qf[s], kf, sacc[ni], 0, 0, 0);
            }
        if (kt == qt) {
#pragma unroll
            for (int ni = 0; ni < 4; ni++)
#pragma unroll
                for (int r = 0; r < 4; r++) {
                    float v = sacc[ni][r] * 0.125f;
                    sacc[ni][r] = (ni*16 + fr > w*16 + fc*4 + r) ? -INFINITY : v;
                }
        } else {
#pragma unroll
            for (int ni = 0; ni < 4; ni++)
#pragma unroll
                for (int r = 0; r < 4; r++) sacc[ni][r] *= 0.125f;
        }
        // ---- online softmax ----
        float p[4][4];
#pragma unroll
        for (int r = 0; r < 4; r++) {
            float mx = fmaxf(fmaxf(sacc[0][r], sacc[1][r]), fmaxf(sacc[2][r], sacc[3][r]));
#pragma unroll
            for (int o = 1; o < 16; o <<= 1) mx = fmaxf(mx, __shfl_xor(mx, o, 64));
            float mn = fmaxf(m[r], mx);
            float fac = __expf(m[r] - mn);
            float rs = 0.f;
#pragma unroll
            for (int ni = 0; ni < 4; ni++) {
                float pv = __expf(sacc[ni][r] - mn);
                p[ni][r] = pv;
                rs += pv;
            }
#pragma unroll
            for (int o = 1; o < 16; o <<= 1) rs += __shfl_xor(rs, o, 64);
            l[r] = l[r] * fac + rs;
            m[r] = mn;
#pragma unroll
            for (int ni = 0; ni < 4; ni++) oacc[ni][r] *= fac;
        }
#pragma unroll
        for (int ni = 0; ni < 4; ni++)
#pragma unroll
            for (int r = 0; r < 4; r++)
                Ps[w][fc*4 + r][ni*16 + fr] = f2bs(p[ni][r]);
        bf16x8 pa[2];
#pragma unroll
        for (int s = 0; s < 2; s++) pa[s] = *(const bf16x8*)&Ps[w][fr][s*32 + fc*8];
#pragma unroll
        for (int ni = 0; ni < 4; ni++)
#pragma unroll
            for (int s = 0; s < 2; s++) {
                bf16x8 vf = *(const bf16x8*)&Vs[cur][ni*16 + fr][((s*4 + fc) ^ (fr & 7))*8];
                oacc[ni] = __builtin_amdgcn_mfma_f32_16x16x32_bf16(pa[s], vf, oacc[ni], 0, 0, 0);
            }
        asm volatile("s_waitcnt vmcnt(0)" ::: "memory");
        __syncthreads();
        cur ^= 1;
    }
#pragma unroll
    for (int r = 0; r < 4; r++) {
        float rinv = 1.f / l[r];
        int row = b*SS + q0 + w*16 + fc*4 + r;
#pragma unroll
        for (int ni = 0; ni < 4; ni++)
            y[(size_t)row*D + h*HD + ni*16 + fr] = __float2bfloat16(oacc[ni][r] * rinv);
    }
}

extern "C" void kernel_launch(void* const* d_in, const int* in_sizes, int n_in,
                              void* d_out, int out_size, void* d_ws, size_t ws_size,
                              hipStream_t stream) {
    const int*   idx  = (const int*)d_in[0];
    const float* tok  = (const float*)d_in[1];
    const float* pos  = (const float*)d_in[2];
    const float* ln1w = (const float*)d_in[3];
    const float* ln1b = (const float*)d_in[4];
    const float* Wq   = (const float*)d_in[5];
    const float* bq   = (const float*)d_in[6];
    const float* Wk   = (const float*)d_in[7];
    const float* bk   = (const float*)d_in[8];
    const float* Wv   = (const float*)d_in[9];
    const float* bv   = (const float*)d_in[10];
    const float* Wo   = (const float*)d_in[11];
    const float* bo   = (const float*)d_in[12];
    const float* ln2w = (const float*)d_in[13];
    const float* ln2b = (const float*)d_in[14];
    const float* W1   = (const float*)d_in[15];
    const float* b1   = (const float*)d_in[16];
    const float* W2   = (const float*)d_in[17];
    const float* b2   = (const float*)d_in[18];
    const float* lnfw = (const float*)d_in[19];
    const float* lnfb = (const float*)d_in[20];
    const float* lmw  = (const float*)d_in[21];
    float* out = (float*)d_out;

    // ---- workspace carve ----
    char* p = (char*)d_ws;
    __hip_bfloat16* qkvT = (__hip_bfloat16*)p; p += (size_t)NL*QKVN*D*2;
    __hip_bfloat16* WoT  = (__hip_bfloat16*)p; p += (size_t)NL*D*D*2;
    __hip_bfloat16* W1T  = (__hip_bfloat16*)p; p += (size_t)NL*DFF*D*2;
    __hip_bfloat16* W2T  = (__hip_bfloat16*)p; p += (size_t)NL*D*DFF*2;
    __hip_bfloat16* lmT  = (__hip_bfloat16*)p; p += (size_t)VOCAB*D*2;
    float*          bqkv = (float*)p;          p += (size_t)NL*QKVN*4;
    float*          x    = (float*)p;          p += (size_t)NROWS*D*4;
    __hip_bfloat16* h    = (__hip_bfloat16*)p; p += (size_t)NROWS*D*2;
    __hip_bfloat16* qkv  = (__hip_bfloat16*)p; p += (size_t)NROWS*QKVN*2;
    __hip_bfloat16* vt   = (__hip_bfloat16*)p; p += (size_t)BB*NH*HD*SS*2;
    __hip_bfloat16* yb   = (__hip_bfloat16*)p; p += (size_t)NROWS*D*2;
    __hip_bfloat16* a1   = (__hip_bfloat16*)p; p += (size_t)NROWS*DFF*2;

    // ---- weight conversion / transposition ----
    dim3 tDD(D/32, D/32, NL);
    transpose_cvt<<<tDD, 256, 0, stream>>>(Wq, qkvT, D, D, (size_t)D*D, (size_t)QKVN*D, 0);
    transpose_cvt<<<tDD, 256, 0, stream>>>(Wk, qkvT, D, D, (size_t)D*D, (size_t)QKVN*D, D);
    transpose_cvt<<<tDD, 256, 0, stream>>>(Wv, qkvT, D, D, (size_t)D*D, (size_t)QKVN*D, 2*D);
    transpose_cvt<<<tDD, 256, 0, stream>>>(Wo, WoT, D, D, (size_t)D*D, (size_t)D*D, 0);
    transpose_cvt<<<dim3(D/32, DFF/32, NL), 256, 0, stream>>>(W1, W1T, D, DFF, (size_t)D*DFF, (size_t)DFF*D, 0);
    transpose_cvt<<<dim3(DFF/32, D/32, NL), 256, 0, stream>>>(W2, W2T, DFF, D, (size_t)DFF*D, (size_t)D*DFF, 0);
    transpose_cvt<<<dim3(D/32, VOCAB/32, 1), 256, 0, stream>>>(lmw, lmT, D, VOCAB, 0, 0, 0);
    pack_qkv_bias<<<dim3(3, NL), 256, 0, stream>>>(bq, bk, bv, bqkv);

    embed_kernel<<<NROWS, 256, 0, stream>>>(idx, tok, pos, x);

    for (int l = 0; l < NL; l++) {
        layernorm_kernel<<<NROWS, 256, 0, stream>>>(x, ln1w + l*D, ln1b + l*D, h);
        gemm_mfma<128,64,0,__hip_bfloat16,0,0,1><<<576, 256, 0, stream>>>(
            (const ushort*)h, (const ushort*)(qkvT + (size_t)l*QKVN*D),
            bqkv + (size_t)l*QKVN, nullptr, qkv, QKVN, D, QKVN/64, NROWS/128);
        vtrans_kernel<<<dim3(2, SS/32, BB*NH), 256, 0, stream>>>((const ushort*)qkv, (ushort*)vt);
        attn_mfma<<<BB*NH*(SS/64), 256, 0, stream>>>((const ushort*)qkv, (const ushort*)vt, yb);
        gemm_mfma<64,64,0,float,0,1,1><<<384, 256, 0, stream>>>(
            (const ushort*)yb, (const ushort*)(WoT + (size_t)l*D*D),
            bo + (size_t)l*D, x, x, D, D, D/64, NROWS/64);
        layernorm_kernel<<<NROWS, 256, 0, stream>>>(x, ln2w + l*D, ln2b + l*D, h);
        gemm_mfma<128,128,0,__hip_bfloat16,1,0,1><<<384, 256, 0, stream>>>(
            (const ushort*)h, (const ushort*)(W1T + (size_t)l*DFF*D),
            b1 + (size_t)l*DFF, nullptr, a1, DFF, D, DFF/128, NROWS/128);
        gemm_mfma<64,64,0,float,0,1,1><<<384, 256, 0, stream>>>(
            (const ushort*)a1, (const ushort*)(W2T + (size_t)l*D*DFF),
            b2 + (size_t)l*D, x, x, D, DFF, D/64, NROWS/64);
    }
    layernorm_kernel<<<NROWS, 256, 0, stream>>>(x, lnfw, lnfb, h);
    gemm_mfma<128,128,1,float,0,0,0><<<4000, 256, 0, stream>>>(
        (const ushort*)h, (const ushort*)lmT, nullptr, nullptr, out, VOCAB, D,
        VOCAB/128, NROWS/128);
}